// Round 1
// baseline (6564.989 us; speedup 1.0000x reference)
//
#include <hip/hip_runtime.h>
#include <math.h>

#define BB 4
#define SS 512
#define SE 512
#define DD 1024
#define HH 16
#define FFD 4096
#define NHOP 6

// ---------------- block reduction (256 threads = 4 waves) ----------------
__device__ __forceinline__ float blockSum256(float v, float* s4) {
#pragma unroll
  for (int m = 32; m >= 1; m >>= 1) v += __shfl_xor(v, m);
  __syncthreads();
  if ((threadIdx.x & 63) == 0) s4[threadIdx.x >> 6] = v;
  __syncthreads();
  return s4[0] + s4[1] + s4[2] + s4[3];
}

// ---------------- sincos position/time codes (fp64, matches numpy) -------
__global__ void sincos_kernel(float* __restrict__ out, int n) {
  for (int i = blockIdx.x * blockDim.x + threadIdx.x; i < n;
       i += gridDim.x * blockDim.x) {
    int p = i >> 10, d = i & 1023, j = d >> 1;
    double ang = (double)p / pow(10000.0, (2.0 * j) / 1024.0);
    out[i] = (float)((d & 1) ? cos(ang) : sin(ang));
  }
}

// ---------------- embedding gather * sqrt(D) ------------------------------
__global__ void embed_kernel(const int* __restrict__ tok,
                             const float* __restrict__ emb,
                             float* __restrict__ out, int n) {
  for (int i = blockIdx.x * blockDim.x + threadIdx.x; i < n;
       i += gridDim.x * blockDim.x) {
    int row = i >> 10, d = i & 1023;
    out[i] = emb[(size_t)tok[row] * DD + d] * 32.0f;
  }
}

// ---------------- tensor + pos_codes[s] + time_codes[hop] ----------------
__global__ void addcodes_kernel(float* __restrict__ tin,
                                const float* __restrict__ ten,
                                const float* __restrict__ pos,
                                const float* __restrict__ tim, int hop, int n) {
  for (int i = blockIdx.x * blockDim.x + threadIdx.x; i < n;
       i += gridDim.x * blockDim.x) {
    int d = i & 1023, s = (i >> 10) & 511;
    tin[i] = ten[i] + pos[(s << 10) | d] + tim[(hop << 10) | d];
  }
}

// ---------------- ACT halting: p = sigmoid(x.act_w + b), recurrence ------
__global__ __launch_bounds__(256)
void act_kernel(const float* __restrict__ tin, const float* __restrict__ aw,
                const float* __restrict__ ab, float* __restrict__ hp,
                float* __restrict__ rem, float* __restrict__ uw) {
  __shared__ float s4[4];
  int row = blockIdx.x;
  const float* x = tin + (size_t)row * DD;
  float s = 0.f;
#pragma unroll
  for (int k = 0; k < 4; ++k) {
    int d = threadIdx.x + k * 256;
    s += x[d] * aw[d];
  }
  float z = blockSum256(s, s4);
  if (threadIdx.x == 0) {
    z += ab[0];
    float p = 1.0f / (1.0f + expf(-z));
    float h = hp[row], rm = rem[row];
    float s0 = (h < 1.0f) ? 1.0f : 0.0f;          // still
    float cond = h + p * s0;
    float nh = (cond > 0.99f) ? s0 : 0.0f;        // new_halted
    float s1 = (cond <= 0.99f) ? s0 : 0.0f;       // still'
    h = h + p * s1;
    rm = rm + nh * (1.0f - h);
    h = h + nh * rm;
    hp[row] = h;
    rem[row] = rm;
    uw[row] = p * s1 + nh * rm;
  }
}

// ---------------- fused residual + LayerNorm ------------------------------
__global__ __launch_bounds__(256)
void lnres_kernel(const float* __restrict__ a, const float* __restrict__ r,
                  const float* __restrict__ g, const float* __restrict__ be,
                  float* __restrict__ out) {
  __shared__ float s4[4];
  int row = blockIdx.x;
  size_t base = (size_t)row * DD;
  float x[4];
#pragma unroll
  for (int k = 0; k < 4; ++k) {
    int d = threadIdx.x + k * 256;
    x[k] = a[base + d] + r[base + d];
  }
  float mean = blockSum256(x[0] + x[1] + x[2] + x[3], s4) * (1.0f / 1024.0f);
  float q = 0.f;
#pragma unroll
  for (int k = 0; k < 4; ++k) {
    float dv = x[k] - mean;
    q += dv * dv;
  }
  float var = blockSum256(q, s4) * (1.0f / 1024.0f);
  float inv = 1.0f / sqrtf(var + 1e-12f);
#pragma unroll
  for (int k = 0; k < 4; ++k) {
    int d = threadIdx.x + k * 256;
    out[base + d] = (x[k] - mean) * inv * g[d] + be[d];
  }
}

// ---------------- prev = ten*uw + prev*(1-uw) -----------------------------
__global__ void prev_kernel(const float* __restrict__ ten,
                            const float* __restrict__ uw,
                            float* __restrict__ out, int n) {
  for (int i = blockIdx.x * blockDim.x + threadIdx.x; i < n;
       i += gridDim.x * blockDim.x) {
    float u = uw[i >> 10];
    out[i] = ten[i] * u + out[i] * (1.0f - u);
  }
}

// ---------------- fp32 tiled GEMM: C = A[MxK] @ W[KxN] + bias ------------
// epi: 0 = bias, 1 = (acc+bias)*scale, 2 = relu(acc+bias)
__global__ __launch_bounds__(256)
void gemm_kernel(const float* __restrict__ A, const float* __restrict__ W,
                 const float* __restrict__ bias, float* __restrict__ C, int M,
                 int N, int K, int epi, float scale) {
  __shared__ __align__(16) float AsT[16][68];  // [k][m], stride 68: aligned b128 reads
  __shared__ __align__(16) float Ws[16][64];
  const int tid = threadIdx.x;
  const int tx = tid & 15, ty = tid >> 4;
  const int m0 = blockIdx.y << 6, n0 = blockIdx.x << 6;
  const int ar = tid >> 2, ac4 = tid & 3;
  const int wr = tid >> 4, wc4 = tid & 15;
  float acc[4][4] = {};
  const int nk = K >> 4;
  for (int kt = 0; kt < nk; ++kt) {
    const int k0 = kt << 4;
    __syncthreads();
    float4 va = *(const float4*)(A + (size_t)(m0 + ar) * K + k0 + (ac4 << 2));
    AsT[(ac4 << 2) + 0][ar] = va.x;
    AsT[(ac4 << 2) + 1][ar] = va.y;
    AsT[(ac4 << 2) + 2][ar] = va.z;
    AsT[(ac4 << 2) + 3][ar] = va.w;
    float4 vw = *(const float4*)(W + (size_t)(k0 + wr) * N + n0 + (wc4 << 2));
    *(float4*)&Ws[wr][wc4 << 2] = vw;
    __syncthreads();
#pragma unroll
    for (int kk = 0; kk < 16; ++kk) {
      float4 a = *(const float4*)&AsT[kk][ty << 2];
      float4 b = *(const float4*)&Ws[kk][tx << 2];
      float av[4] = {a.x, a.y, a.z, a.w};
      float bv[4] = {b.x, b.y, b.z, b.w};
#pragma unroll
      for (int i = 0; i < 4; ++i)
#pragma unroll
        for (int j = 0; j < 4; ++j) acc[i][j] += av[i] * bv[j];
    }
  }
#pragma unroll
  for (int i = 0; i < 4; ++i) {
    int row = m0 + (ty << 2) + i;
    int col = n0 + (tx << 2);
    float4 bz = *(const float4*)(bias + col);
    float4 o;
    o.x = acc[i][0] + bz.x;
    o.y = acc[i][1] + bz.y;
    o.z = acc[i][2] + bz.z;
    o.w = acc[i][3] + bz.w;
    if (epi == 1) {
      o.x *= scale; o.y *= scale; o.z *= scale; o.w *= scale;
    } else if (epi == 2) {
      o.x = fmaxf(o.x, 0.f); o.y = fmaxf(o.y, 0.f);
      o.z = fmaxf(o.z, 0.f); o.w = fmaxf(o.w, 0.f);
    }
    *(float4*)(C + (size_t)row * N + col) = o;
  }
}

// ---------------- flash attention (fp32, online softmax) -----------------
// grid (Sq/64, H, B). Q pre-scaled by 1/8. layout [B,S,D], head slice h*64.
__global__ __launch_bounds__(256)
void flash_kernel(const float* __restrict__ Qg, const float* __restrict__ Kg,
                  const float* __restrict__ Vg, float* __restrict__ Og,
                  const int* __restrict__ mask, int Sq, int Sk, int causal) {
  __shared__ __align__(16) float Qs[64][65];
  __shared__ __align__(16) float Ks[64][65];
  __shared__ __align__(16) float Vs[64][64];
  __shared__ __align__(16) float Ps[64][65];
  __shared__ int Ms[64];
  const int tid = threadIdx.x;
  const int tx = tid & 15, ty = tid >> 4;
  const int qt = blockIdx.x, h = blockIdx.y, b = blockIdx.z;
  const size_t qbase = ((size_t)b * Sq + (qt << 6)) * DD + (h << 6);

#pragma unroll
  for (int L = 0; L < 4; ++L) {
    int idx = tid + (L << 8);
    int r = idx >> 4, c4 = idx & 15;
    float4 v = *(const float4*)(Qg + qbase + (size_t)r * DD + (c4 << 2));
    Qs[r][(c4 << 2) + 0] = v.x;
    Qs[r][(c4 << 2) + 1] = v.y;
    Qs[r][(c4 << 2) + 2] = v.z;
    Qs[r][(c4 << 2) + 3] = v.w;
  }
  float m_[4], l_[4], o_[4][4];
#pragma unroll
  for (int i = 0; i < 4; ++i) {
    m_[i] = -3.0e38f;
    l_[i] = 0.f;
#pragma unroll
    for (int j = 0; j < 4; ++j) o_[i][j] = 0.f;
  }
  const int nkt = causal ? (qt + 1) : (Sk >> 6);
  for (int kt = 0; kt < nkt; ++kt) {
    __syncthreads();
    const size_t kbase = ((size_t)b * Sk + (kt << 6)) * DD + (h << 6);
#pragma unroll
    for (int L = 0; L < 4; ++L) {
      int idx = tid + (L << 8);
      int r = idx >> 4, c4 = idx & 15;
      float4 vk = *(const float4*)(Kg + kbase + (size_t)r * DD + (c4 << 2));
      Ks[r][(c4 << 2) + 0] = vk.x;
      Ks[r][(c4 << 2) + 1] = vk.y;
      Ks[r][(c4 << 2) + 2] = vk.z;
      Ks[r][(c4 << 2) + 3] = vk.w;
      float4 vv = *(const float4*)(Vg + kbase + (size_t)r * DD + (c4 << 2));
      *(float4*)&Vs[r][c4 << 2] = vv;
    }
    if (mask != nullptr && tid < 64) Ms[tid] = mask[b * Sk + (kt << 6) + tid];
    __syncthreads();
    float s[4][4] = {};
#pragma unroll 8
    for (int d = 0; d < 64; ++d) {
      float a[4], bq[4];
#pragma unroll
      for (int i = 0; i < 4; ++i) a[i] = Qs[(ty << 2) + i][d];
#pragma unroll
      for (int j = 0; j < 4; ++j) bq[j] = Ks[(tx << 2) + j][d];
#pragma unroll
      for (int i = 0; i < 4; ++i)
#pragma unroll
        for (int j = 0; j < 4; ++j) s[i][j] += a[i] * bq[j];
    }
    if (causal && kt == qt) {
#pragma unroll
      for (int i = 0; i < 4; ++i)
#pragma unroll
        for (int j = 0; j < 4; ++j)
          if (((tx << 2) + j) > ((ty << 2) + i)) s[i][j] = -1e20f;
    }
    if (mask != nullptr) {
#pragma unroll
      for (int j = 0; j < 4; ++j)
        if (Ms[(tx << 2) + j] == 0) {
#pragma unroll
          for (int i = 0; i < 4; ++i) s[i][j] = -1e20f;
        }
    }
#pragma unroll
    for (int i = 0; i < 4; ++i) {
      float rmax = fmaxf(fmaxf(s[i][0], s[i][1]), fmaxf(s[i][2], s[i][3]));
#pragma unroll
      for (int mk = 1; mk < 16; mk <<= 1) rmax = fmaxf(rmax, __shfl_xor(rmax, mk));
      float mn = fmaxf(m_[i], rmax);
      float f = expf(m_[i] - mn);
      float pi[4];
      float rs = 0.f;
#pragma unroll
      for (int j = 0; j < 4; ++j) {
        pi[j] = expf(s[i][j] - mn);
        rs += pi[j];
      }
#pragma unroll
      for (int mk = 1; mk < 16; mk <<= 1) rs += __shfl_xor(rs, mk);
      l_[i] = l_[i] * f + rs;
#pragma unroll
      for (int j = 0; j < 4; ++j) o_[i][j] *= f;
      m_[i] = mn;
#pragma unroll
      for (int j = 0; j < 4; ++j) Ps[(ty << 2) + i][(tx << 2) + j] = pi[j];
    }
    __syncthreads();
#pragma unroll 8
    for (int kc = 0; kc < 64; ++kc) {
      float pv[4];
#pragma unroll
      for (int i = 0; i < 4; ++i) pv[i] = Ps[(ty << 2) + i][kc];
      float4 vv = *(const float4*)&Vs[kc][tx << 2];
      float vj[4] = {vv.x, vv.y, vv.z, vv.w};
#pragma unroll
      for (int i = 0; i < 4; ++i)
#pragma unroll
        for (int j = 0; j < 4; ++j) o_[i][j] += pv[i] * vj[j];
    }
  }
#pragma unroll
  for (int i = 0; i < 4; ++i) {
    float inv = 1.0f / l_[i];
    float4 o;
    o.x = o_[i][0] * inv;
    o.y = o_[i][1] * inv;
    o.z = o_[i][2] * inv;
    o.w = o_[i][3] * inv;
    *(float4*)(Og + qbase + (size_t)((ty << 2) + i) * DD + (tx << 2)) = o;
  }
}

// --------------------------------------------------------------------------
extern "C" void kernel_launch(void* const* d_in, const int* in_sizes, int n_in,
                              void* d_out, int out_size, void* d_ws,
                              size_t ws_size, hipStream_t stream) {
  const int* tokens = (const int*)d_in[0];
  const float* enc = (const float*)d_in[1];
  const int* encmask = (const int*)d_in[2];
  const float* emb = (const float*)d_in[3];
  const float* sa_qw = (const float*)d_in[4];
  const float* sa_qb = (const float*)d_in[5];
  const float* sa_kw = (const float*)d_in[6];
  const float* sa_kb = (const float*)d_in[7];
  const float* sa_vw = (const float*)d_in[8];
  const float* sa_vb = (const float*)d_in[9];
  const float* sa_ow = (const float*)d_in[10];
  const float* sa_ob = (const float*)d_in[11];
  const float* ca_qw = (const float*)d_in[12];
  const float* ca_qb = (const float*)d_in[13];
  const float* ca_kw = (const float*)d_in[14];
  const float* ca_kb = (const float*)d_in[15];
  const float* ca_vw = (const float*)d_in[16];
  const float* ca_vb = (const float*)d_in[17];
  const float* ca_ow = (const float*)d_in[18];
  const float* ca_ob = (const float*)d_in[19];
  const float* ln1_g = (const float*)d_in[20];
  const float* ln1_b = (const float*)d_in[21];
  const float* ln2_g = (const float*)d_in[22];
  const float* ln2_b = (const float*)d_in[23];
  const float* ln3_g = (const float*)d_in[24];
  const float* ln3_b = (const float*)d_in[25];
  const float* ff_w1 = (const float*)d_in[26];
  const float* ff_b1 = (const float*)d_in[27];
  const float* ff_w2 = (const float*)d_in[28];
  const float* ff_b2 = (const float*)d_in[29];
  const float* act_w = (const float*)d_in[30];
  const float* act_b = (const float*)d_in[31];
  float* out = (float*)d_out;

  const size_t nbsd = (size_t)BB * SS * DD;  // 2097152
  const size_t nff = (size_t)BB * SS * FFD;  // 8388608
  const size_t nbs = (size_t)BB * SS;        // 2048

  float* w = (float*)d_ws;
  float* POS = w;  w += (size_t)SS * DD;
  float* TIM = w;  w += (size_t)NHOP * DD;
  float* ENCK = w; w += nbsd;
  float* ENCV = w; w += nbsd;
  float* TEN = w;  w += nbsd;
  float* TIN = w;  w += nbsd;
  float* Qb = w;   w += nbsd;
  float* Kb = w;   w += nbsd;  // also reused as T2 after self-attn
  float* Vb = w;   w += nbsd;  // also reused as T3 after cross-attn
  float* AO = w;   w += nbsd;
  float* PR = w;   w += nbsd;
  float* FFH = w;  w += nff;
  float* HPp = w;  w += nbs;
  float* REMp = w; w += nbs;
  float* UWp = w;  w += nbs;
  size_t need = (size_t)(w - (float*)d_ws) * sizeof(float);
  if (ws_size < need) return;  // insufficient scratch; bail

  hipMemsetAsync(d_out, 0, nbsd * sizeof(float), stream);
  hipMemsetAsync(HPp, 0, 2 * nbs * sizeof(float), stream);  // hp, rem
  sincos_kernel<<<dim3(512), dim3(256), 0, stream>>>(POS, SS * DD);
  sincos_kernel<<<dim3(24), dim3(256), 0, stream>>>(TIM, NHOP * DD);
  embed_kernel<<<dim3(2048), dim3(256), 0, stream>>>(tokens, emb, TEN, (int)nbsd);

  auto gemm = [&](const float* A, const float* Wm, const float* bi, float* C,
                  int M, int N, int K, int epi, float sc) {
    gemm_kernel<<<dim3(N >> 6, M >> 6), dim3(256), 0, stream>>>(A, Wm, bi, C, M,
                                                                N, K, epi, sc);
  };

  // hoisted: encoder K/V projections (constant across hops)
  gemm(enc, ca_kw, ca_kb, ENCK, BB * SE, DD, DD, 0, 1.f);
  gemm(enc, ca_vw, ca_vb, ENCV, BB * SE, DD, DD, 0, 1.f);

  for (int t = 0; t < NHOP; ++t) {
    addcodes_kernel<<<dim3(2048), dim3(256), 0, stream>>>(TIN, TEN, POS, TIM, t,
                                                          (int)nbsd);
    act_kernel<<<dim3(2048), dim3(256), 0, stream>>>(TIN, act_w, act_b, HPp,
                                                     REMp, UWp);
    // self-attention
    gemm(TIN, sa_qw, sa_qb, Qb, 2048, DD, DD, 1, 0.125f);
    gemm(TIN, sa_kw, sa_kb, Kb, 2048, DD, DD, 0, 1.f);
    gemm(TIN, sa_vw, sa_vb, Vb, 2048, DD, DD, 0, 1.f);
    flash_kernel<<<dim3(8, HH, BB), dim3(256), 0, stream>>>(Qb, Kb, Vb, AO,
                                                            nullptr, SS, SS, 1);
    gemm(AO, sa_ow, sa_ob, PR, 2048, DD, DD, 0, 1.f);
    lnres_kernel<<<dim3(2048), dim3(256), 0, stream>>>(PR, TIN, ln1_g, ln1_b,
                                                       Kb);  // T2 = Kb
    // cross-attention
    gemm(Kb, ca_qw, ca_qb, Qb, 2048, DD, DD, 1, 0.125f);
    flash_kernel<<<dim3(8, HH, BB), dim3(256), 0, stream>>>(
        Qb, ENCK, ENCV, AO, encmask, SS, SE, 0);
    gemm(AO, ca_ow, ca_ob, PR, 2048, DD, DD, 0, 1.f);
    lnres_kernel<<<dim3(2048), dim3(256), 0, stream>>>(PR, Kb, ln2_g, ln2_b,
                                                       Vb);  // T3 = Vb
    // FFN
    gemm(Vb, ff_w1, ff_b1, FFH, 2048, FFD, DD, 2, 1.f);
    gemm(FFH, ff_w2, ff_b2, PR, 2048, DD, FFD, 0, 1.f);
    lnres_kernel<<<dim3(2048), dim3(256), 0, stream>>>(PR, Vb, ln3_g, ln3_b,
                                                       TEN);
    // prev = tensor*uw + prev*(1-uw)
    prev_kernel<<<dim3(2048), dim3(256), 0, stream>>>(TEN, UWp, out, (int)nbsd);
  }
}

// Round 2
// 3693.267 us; speedup vs baseline: 1.7776x; 1.7776x over previous
//
#include <hip/hip_runtime.h>
#include <math.h>

#define BB 4
#define SS 512
#define SE 512
#define DD 1024
#define HH 16
#define FFD 4096
#define NHOP 6

typedef float f4 __attribute__((ext_vector_type(4)));
typedef float f32x4 __attribute__((ext_vector_type(4)));
typedef _Float16 h8 __attribute__((ext_vector_type(8)));

#define GLD16(gp, lp)                                                     \
  __builtin_amdgcn_global_load_lds(                                       \
      (const __attribute__((address_space(1))) void*)(gp),                \
      (__attribute__((address_space(3))) void*)(lp), 16, 0, 0)

// ---------------- block reduction (256 threads = 4 waves) ----------------
__device__ __forceinline__ float blockSum256(float v, float* s4) {
#pragma unroll
  for (int m = 32; m >= 1; m >>= 1) v += __shfl_xor(v, m);
  __syncthreads();
  if ((threadIdx.x & 63) == 0) s4[threadIdx.x >> 6] = v;
  __syncthreads();
  return s4[0] + s4[1] + s4[2] + s4[3];
}

// ---------------- sincos position/time codes (fp64, matches numpy) -------
__global__ void sincos_kernel(float* __restrict__ out, int n) {
  for (int i = blockIdx.x * blockDim.x + threadIdx.x; i < n;
       i += gridDim.x * blockDim.x) {
    int p = i >> 10, d = i & 1023, j = d >> 1;
    double ang = (double)p / pow(10000.0, (2.0 * j) / 1024.0);
    out[i] = (float)((d & 1) ? cos(ang) : sin(ang));
  }
}

// ---------------- embedding gather * sqrt(D) ------------------------------
__global__ void embed_kernel(const int* __restrict__ tok,
                             const float* __restrict__ emb,
                             float* __restrict__ out, int n) {
  for (int i = blockIdx.x * blockDim.x + threadIdx.x; i < n;
       i += gridDim.x * blockDim.x) {
    int row = i >> 10, d = i & 1023;
    out[i] = emb[(size_t)tok[row] * DD + d] * 32.0f;
  }
}

// ---------------- tensor + pos_codes[s] + time_codes[hop] ----------------
__global__ void addcodes_kernel(float* __restrict__ tin,
                                const float* __restrict__ ten,
                                const float* __restrict__ pos,
                                const float* __restrict__ tim, int hop, int n) {
  for (int i = blockIdx.x * blockDim.x + threadIdx.x; i < n;
       i += gridDim.x * blockDim.x) {
    int d = i & 1023, s = (i >> 10) & 511;
    tin[i] = ten[i] + pos[(s << 10) | d] + tim[(hop << 10) | d];
  }
}

// ---------------- ACT halting ------------------------------------------
__global__ __launch_bounds__(256)
void act_kernel(const float* __restrict__ tin, const float* __restrict__ aw,
                const float* __restrict__ ab, float* __restrict__ hp,
                float* __restrict__ rem, float* __restrict__ uw) {
  __shared__ float s4[4];
  int row = blockIdx.x;
  const float* x = tin + (size_t)row * DD;
  float s = 0.f;
#pragma unroll
  for (int k = 0; k < 4; ++k) {
    int d = threadIdx.x + k * 256;
    s += x[d] * aw[d];
  }
  float z = blockSum256(s, s4);
  if (threadIdx.x == 0) {
    z += ab[0];
    float p = 1.0f / (1.0f + expf(-z));
    float h = hp[row], rm = rem[row];
    float s0 = (h < 1.0f) ? 1.0f : 0.0f;
    float cond = h + p * s0;
    float nh = (cond > 0.99f) ? s0 : 0.0f;
    float s1 = (cond <= 0.99f) ? s0 : 0.0f;
    h = h + p * s1;
    rm = rm + nh * (1.0f - h);
    h = h + nh * rm;
    hp[row] = h;
    rem[row] = rm;
    uw[row] = p * s1 + nh * rm;
  }
}

// ---------------- fused residual + LayerNorm ------------------------------
__global__ __launch_bounds__(256)
void lnres_kernel(const float* __restrict__ a, const float* __restrict__ r,
                  const float* __restrict__ g, const float* __restrict__ be,
                  float* __restrict__ out) {
  __shared__ float s4[4];
  int row = blockIdx.x;
  size_t base = (size_t)row * DD;
  float x[4];
#pragma unroll
  for (int k = 0; k < 4; ++k) {
    int d = threadIdx.x + k * 256;
    x[k] = a[base + d] + r[base + d];
  }
  float mean = blockSum256(x[0] + x[1] + x[2] + x[3], s4) * (1.0f / 1024.0f);
  float q = 0.f;
#pragma unroll
  for (int k = 0; k < 4; ++k) {
    float dv = x[k] - mean;
    q += dv * dv;
  }
  float var = blockSum256(q, s4) * (1.0f / 1024.0f);
  float inv = 1.0f / sqrtf(var + 1e-12f);
#pragma unroll
  for (int k = 0; k < 4; ++k) {
    int d = threadIdx.x + k * 256;
    out[base + d] = (x[k] - mean) * inv * g[d] + be[d];
  }
}

// ---------------- prev = ten*uw + prev*(1-uw) -----------------------------
__global__ void prev_kernel(const float* __restrict__ ten,
                            const float* __restrict__ uw,
                            float* __restrict__ out, int n) {
  for (int i = blockIdx.x * blockDim.x + threadIdx.x; i < n;
       i += gridDim.x * blockDim.x) {
    float u = uw[i >> 10];
    out[i] = ten[i] * u + out[i] * (1.0f - u);
  }
}

// ---------------- weight transpose + fp16 hi/lo split --------------------
// W[K][N] fp32 -> WhT[N][K], WlT[N][K] fp16
__global__ __launch_bounds__(256)
void wsplit_kernel(const float* __restrict__ W, _Float16* __restrict__ WhT,
                   _Float16* __restrict__ WlT, int K, int N) {
  __shared__ float t[32][33];
  int k0 = blockIdx.y << 5, n0 = blockIdx.x << 5;
  int c = threadIdx.x & 31, r8 = threadIdx.x >> 5;
  for (int rr = r8; rr < 32; rr += 8)
    t[rr][c] = W[(size_t)(k0 + rr) * N + n0 + c];
  __syncthreads();
  for (int rr = r8; rr < 32; rr += 8) {
    float v = t[c][rr];
    _Float16 hh = (_Float16)v;
    WhT[(size_t)(n0 + rr) * K + k0 + c] = hh;
    WlT[(size_t)(n0 + rr) * K + k0 + c] = (_Float16)(v - (float)hh);
  }
}

// ---------------- split-fp16 MFMA GEMM -----------------------------------
// C[M,N] = A[M,K] @ W[K,N] + bias, via 3-product fp16 emulation.
// A fp32 (reg-staged, split in-kernel), W pre-split/transposed fp16 planes.
// FM = A-frags per wave in M (MT = 32*FM). N tile fixed 128, BK=32, 4 waves.
// LDS XOR slot-swizzle (swizzled source, linear dest, swizzled read).
template <int FM>
__global__ __launch_bounds__(256) void gemm_mfma(
    const float* __restrict__ A, const _Float16* __restrict__ BhT,
    const _Float16* __restrict__ BlT, const float* __restrict__ bias,
    float* __restrict__ C, int M, int N, int K, int epi, float scale) {
  constexpr int MT = FM * 32;
  constexpr int SA = MT / 64;  // 16B A-slots per thread
  __shared__ __align__(16) _Float16 Ah[MT * 32];
  __shared__ __align__(16) _Float16 Al[MT * 32];
  __shared__ __align__(16) _Float16 Bh[128 * 32];
  __shared__ __align__(16) _Float16 Bl[128 * 32];
  const int tid = threadIdx.x;
  const int lane = tid & 63, wid = tid >> 6;
  const int wm = (wid >> 1) * (FM * 16);
  const int wn = (wid & 1) * 64;
  const int m0 = blockIdx.y * MT, n0 = blockIdx.x << 7;
  const int l15 = lane & 15, l4 = lane >> 4;

  f32x4 acc[FM][4];
#pragma unroll
  for (int i = 0; i < FM; ++i)
#pragma unroll
    for (int j = 0; j < 4; ++j) acc[i][j] = (f32x4){0.f, 0.f, 0.f, 0.f};

  const int nk = K >> 5;
  for (int kt = 0; kt < nk; ++kt) {
    // ---- A tile: global -> regs (issued before barrier; overlaps compute)
    f4 ar[SA][2];
#pragma unroll
    for (int s = 0; s < SA; ++s) {
      int slot = tid + (s << 8);
      int m = slot >> 2, sl = slot & 3;
      int k0 = ((sl ^ ((m >> 1) & 3)) << 3);  // inverse swizzle on source
      const float* src = A + (size_t)(m0 + m) * K + (kt << 5) + k0;
      ar[s][0] = *(const f4*)src;
      ar[s][1] = *(const f4*)(src + 4);
    }
    __syncthreads();  // previous compute's LDS reads done
    // ---- W tiles: async global->LDS, 16B, swizzled source / linear dest
#pragma unroll
    for (int c = 0; c < 2; ++c) {
      int ch = (wid << 1) + c;
      int n = (ch << 4) + (lane >> 2), sl = lane & 3;
      int k0 = ((sl ^ ((n >> 1) & 3)) << 3);
      const _Float16* gh = BhT + (size_t)(n0 + n) * K + (kt << 5) + k0;
      const _Float16* gl = BlT + (size_t)(n0 + n) * K + (kt << 5) + k0;
      GLD16(gh, &Bh[ch << 9]);
      GLD16(gl, &Bl[ch << 9]);
    }
    // ---- A tile: split fp32 -> fp16 hi/lo, ds_write (linear slots)
#pragma unroll
    for (int s = 0; s < SA; ++s) {
      int slot = tid + (s << 8);
      int m = slot >> 2, sl = slot & 3;
      h8 hv, lv;
#pragma unroll
      for (int j = 0; j < 8; ++j) {
        float v = (j < 4) ? ar[s][0][j] : ar[s][1][j - 4];
        _Float16 hh = (_Float16)v;
        hv[j] = hh;
        lv[j] = (_Float16)(v - (float)hh);
      }
      *(h8*)&Ah[(m << 5) + (sl << 3)] = hv;
      *(h8*)&Al[(m << 5) + (sl << 3)] = lv;
    }
    __syncthreads();  // drains vmcnt (gload_lds) + lgkm (ds_write)
    // ---- fragments + MFMA
    h8 ah[FM], al[FM], bh[4], bl[4];
#pragma unroll
    for (int fi = 0; fi < FM; ++fi) {
      int m = wm + (fi << 4) + l15;
      int st = (l4 ^ ((m >> 1) & 3));  // swizzled read
      ah[fi] = *(const h8*)&Ah[(m << 5) + (st << 3)];
      al[fi] = *(const h8*)&Al[(m << 5) + (st << 3)];
    }
#pragma unroll
    for (int fj = 0; fj < 4; ++fj) {
      int n = wn + (fj << 4) + l15;
      int st = (l4 ^ ((n >> 1) & 3));
      bh[fj] = *(const h8*)&Bh[(n << 5) + (st << 3)];
      bl[fj] = *(const h8*)&Bl[(n << 5) + (st << 3)];
    }
#pragma unroll
    for (int fi = 0; fi < FM; ++fi)
#pragma unroll
      for (int fj = 0; fj < 4; ++fj) {
        acc[fi][fj] = __builtin_amdgcn_mfma_f32_16x16x32_f16(
            ah[fi], bh[fj], acc[fi][fj], 0, 0, 0);
        acc[fi][fj] = __builtin_amdgcn_mfma_f32_16x16x32_f16(
            al[fi], bh[fj], acc[fi][fj], 0, 0, 0);
        acc[fi][fj] = __builtin_amdgcn_mfma_f32_16x16x32_f16(
            ah[fi], bl[fj], acc[fi][fj], 0, 0, 0);
      }
  }
  // ---- epilogue: C/D layout col=lane&15, row=(lane>>4)*4+r (m89-verified)
#pragma unroll
  for (int fi = 0; fi < FM; ++fi) {
    int row = m0 + wm + (fi << 4) + (l4 << 2);
#pragma unroll
    for (int fj = 0; fj < 4; ++fj) {
      int col = n0 + wn + (fj << 4) + l15;
      float bz = bias[col];
#pragma unroll
      for (int r = 0; r < 4; ++r) {
        float o = acc[fi][fj][r] + bz;
        if (epi == 1) o *= scale;
        else if (epi == 2) o = fmaxf(o, 0.f);
        C[(size_t)(row + r) * N + col] = o;
      }
    }
  }
}

// ---------------- flash attention (fp32, online softmax) -----------------
__global__ __launch_bounds__(256)
void flash_kernel(const float* __restrict__ Qg, const float* __restrict__ Kg,
                  const float* __restrict__ Vg, float* __restrict__ Og,
                  const int* __restrict__ mask, int Sq, int Sk, int causal) {
  __shared__ __align__(16) float Qs[64][65];
  __shared__ __align__(16) float Ks[64][65];
  __shared__ __align__(16) float Vs[64][64];
  __shared__ __align__(16) float Ps[64][65];
  __shared__ int Ms[64];
  const int tid = threadIdx.x;
  const int tx = tid & 15, ty = tid >> 4;
  const int qt = blockIdx.x, h = blockIdx.y, b = blockIdx.z;
  const size_t qbase = ((size_t)b * Sq + (qt << 6)) * DD + (h << 6);

#pragma unroll
  for (int L = 0; L < 4; ++L) {
    int idx = tid + (L << 8);
    int r = idx >> 4, c4 = idx & 15;
    float4 v = *(const float4*)(Qg + qbase + (size_t)r * DD + (c4 << 2));
    Qs[r][(c4 << 2) + 0] = v.x;
    Qs[r][(c4 << 2) + 1] = v.y;
    Qs[r][(c4 << 2) + 2] = v.z;
    Qs[r][(c4 << 2) + 3] = v.w;
  }
  float m_[4], l_[4], o_[4][4];
#pragma unroll
  for (int i = 0; i < 4; ++i) {
    m_[i] = -3.0e38f;
    l_[i] = 0.f;
#pragma unroll
    for (int j = 0; j < 4; ++j) o_[i][j] = 0.f;
  }
  const int nkt = causal ? (qt + 1) : (Sk >> 6);
  for (int kt = 0; kt < nkt; ++kt) {
    __syncthreads();
    const size_t kbase = ((size_t)b * Sk + (kt << 6)) * DD + (h << 6);
#pragma unroll
    for (int L = 0; L < 4; ++L) {
      int idx = tid + (L << 8);
      int r = idx >> 4, c4 = idx & 15;
      float4 vk = *(const float4*)(Kg + kbase + (size_t)r * DD + (c4 << 2));
      Ks[r][(c4 << 2) + 0] = vk.x;
      Ks[r][(c4 << 2) + 1] = vk.y;
      Ks[r][(c4 << 2) + 2] = vk.z;
      Ks[r][(c4 << 2) + 3] = vk.w;
      float4 vv = *(const float4*)(Vg + kbase + (size_t)r * DD + (c4 << 2));
      *(float4*)&Vs[r][c4 << 2] = vv;
    }
    if (mask != nullptr && tid < 64) Ms[tid] = mask[b * Sk + (kt << 6) + tid];
    __syncthreads();
    float s[4][4] = {};
#pragma unroll 8
    for (int d = 0; d < 64; ++d) {
      float a[4], bq[4];
#pragma unroll
      for (int i = 0; i < 4; ++i) a[i] = Qs[(ty << 2) + i][d];
#pragma unroll
      for (int j = 0; j < 4; ++j) bq[j] = Ks[(tx << 2) + j][d];
#pragma unroll
      for (int i = 0; i < 4; ++i)
#pragma unroll
        for (int j = 0; j < 4; ++j) s[i][j] += a[i] * bq[j];
    }
    if (causal && kt == qt) {
#pragma unroll
      for (int i = 0; i < 4; ++i)
#pragma unroll
        for (int j = 0; j < 4; ++j)
          if (((tx << 2) + j) > ((ty << 2) + i)) s[i][j] = -1e20f;
    }
    if (mask != nullptr) {
#pragma unroll
      for (int j = 0; j < 4; ++j)
        if (Ms[(tx << 2) + j] == 0) {
#pragma unroll
          for (int i = 0; i < 4; ++i) s[i][j] = -1e20f;
        }
    }
#pragma unroll
    for (int i = 0; i < 4; ++i) {
      float rmax = fmaxf(fmaxf(s[i][0], s[i][1]), fmaxf(s[i][2], s[i][3]));
#pragma unroll
      for (int mk = 1; mk < 16; mk <<= 1) rmax = fmaxf(rmax, __shfl_xor(rmax, mk));
      float mn = fmaxf(m_[i], rmax);
      float f = expf(m_[i] - mn);
      float pi[4];
      float rs = 0.f;
#pragma unroll
      for (int j = 0; j < 4; ++j) {
        pi[j] = expf(s[i][j] - mn);
        rs += pi[j];
      }
#pragma unroll
      for (int mk = 1; mk < 16; mk <<= 1) rs += __shfl_xor(rs, mk);
      l_[i] = l_[i] * f + rs;
#pragma unroll
      for (int j = 0; j < 4; ++j) o_[i][j] *= f;
      m_[i] = mn;
#pragma unroll
      for (int j = 0; j < 4; ++j) Ps[(ty << 2) + i][(tx << 2) + j] = pi[j];
    }
    __syncthreads();
#pragma unroll 8
    for (int kc = 0; kc < 64; ++kc) {
      float pv[4];
#pragma unroll
      for (int i = 0; i < 4; ++i) pv[i] = Ps[(ty << 2) + i][kc];
      float4 vv = *(const float4*)&Vs[kc][tx << 2];
      float vj[4] = {vv.x, vv.y, vv.z, vv.w};
#pragma unroll
      for (int i = 0; i < 4; ++i)
#pragma unroll
        for (int j = 0; j < 4; ++j) o_[i][j] += pv[i] * vj[j];
    }
  }
#pragma unroll
  for (int i = 0; i < 4; ++i) {
    float inv = 1.0f / l_[i];
    float4 o;
    o.x = o_[i][0] * inv;
    o.y = o_[i][1] * inv;
    o.z = o_[i][2] * inv;
    o.w = o_[i][3] * inv;
    *(float4*)(Og + qbase + (size_t)((ty << 2) + i) * DD + (tx << 2)) = o;
  }
}

// --------------------------------------------------------------------------
extern "C" void kernel_launch(void* const* d_in, const int* in_sizes, int n_in,
                              void* d_out, int out_size, void* d_ws,
                              size_t ws_size, hipStream_t stream) {
  const int* tokens = (const int*)d_in[0];
  const float* enc = (const float*)d_in[1];
  const int* encmask = (const int*)d_in[2];
  const float* emb = (const float*)d_in[3];
  const float* sa_qw = (const float*)d_in[4];
  const float* sa_qb = (const float*)d_in[5];
  const float* sa_kw = (const float*)d_in[6];
  const float* sa_kb = (const float*)d_in[7];
  const float* sa_vw = (const float*)d_in[8];
  const float* sa_vb = (const float*)d_in[9];
  const float* sa_ow = (const float*)d_in[10];
  const float* sa_ob = (const float*)d_in[11];
  const float* ca_qw = (const float*)d_in[12];
  const float* ca_qb = (const float*)d_in[13];
  const float* ca_kw = (const float*)d_in[14];
  const float* ca_kb = (const float*)d_in[15];
  const float* ca_vw = (const float*)d_in[16];
  const float* ca_vb = (const float*)d_in[17];
  const float* ca_ow = (const float*)d_in[18];
  const float* ca_ob = (const float*)d_in[19];
  const float* ln1_g = (const float*)d_in[20];
  const float* ln1_b = (const float*)d_in[21];
  const float* ln2_g = (const float*)d_in[22];
  const float* ln2_b = (const float*)d_in[23];
  const float* ln3_g = (const float*)d_in[24];
  const float* ln3_b = (const float*)d_in[25];
  const float* ff_w1 = (const float*)d_in[26];
  const float* ff_b1 = (const float*)d_in[27];
  const float* ff_w2 = (const float*)d_in[28];
  const float* ff_b2 = (const float*)d_in[29];
  const float* act_w = (const float*)d_in[30];
  const float* act_b = (const float*)d_in[31];
  float* out = (float*)d_out;

  const size_t nbsd = (size_t)BB * SS * DD;  // 2097152
  const size_t nff = (size_t)BB * SS * FFD;  // 8388608
  const size_t nbs = (size_t)BB * SS;        // 2048
  const size_t wsm = (size_t)DD * DD;        // 1M (small weight elems)
  const size_t wff = (size_t)DD * FFD;       // 4M

  float* w = (float*)d_ws;
  float* POS = w;  w += (size_t)SS * DD;
  float* TIM = w;  w += (size_t)NHOP * DD;
  float* ENCK = w; w += nbsd;
  float* ENCV = w; w += nbsd;
  float* TEN = w;  w += nbsd;
  float* TIN = w;  w += nbsd;
  float* Qf = w;   w += nbsd;
  float* Kf = w;   w += nbsd;
  float* Vf = w;   w += nbsd;
  float* AO = w;   w += nbsd;
  float* FFH = w;  w += nff;
  float* HPp = w;  w += nbs;
  float* REMp = w; w += nbs;
  float* UWp = w;  w += nbs;
  // fp16 weight planes (transposed): hi/lo pairs
  _Float16* hp16 = (_Float16*)w;
  auto halloc = [&](size_t n) { _Float16* r = hp16; hp16 += n; return r; };
  _Float16* saqh = halloc(wsm); _Float16* saql = halloc(wsm);
  _Float16* sakh = halloc(wsm); _Float16* sakl = halloc(wsm);
  _Float16* savh = halloc(wsm); _Float16* savl = halloc(wsm);
  _Float16* saoh = halloc(wsm); _Float16* saol = halloc(wsm);
  _Float16* caqh = halloc(wsm); _Float16* caql = halloc(wsm);
  _Float16* cakh = halloc(wsm); _Float16* cakl = halloc(wsm);
  _Float16* cavh = halloc(wsm); _Float16* cavl = halloc(wsm);
  _Float16* caoh = halloc(wsm); _Float16* caol = halloc(wsm);
  _Float16* ff1h = halloc(wff); _Float16* ff1l = halloc(wff);
  _Float16* ff2h = halloc(wff); _Float16* ff2l = halloc(wff);
  size_t need = (size_t)((char*)hp16 - (char*)d_ws);
  if (ws_size < need) return;  // insufficient scratch

  // aliases (lifetime-checked): PR=Vf, T2=Kf, T3=Qf
  float* PR = Vf;
  float* T2 = Kf;
  float* T3 = Qf;

  hipMemsetAsync(d_out, 0, nbsd * sizeof(float), stream);
  hipMemsetAsync(HPp, 0, 2 * nbs * sizeof(float), stream);  // hp, rem
  sincos_kernel<<<dim3(512), dim3(256), 0, stream>>>(POS, SS * DD);
  sincos_kernel<<<dim3(24), dim3(256), 0, stream>>>(TIM, NHOP * DD);
  embed_kernel<<<dim3(2048), dim3(256), 0, stream>>>(tokens, emb, TEN, (int)nbsd);

  // hoisted: weight split+transpose (once per launch)
  auto wsplit = [&](const float* W, _Float16* h, _Float16* l, int K, int N) {
    wsplit_kernel<<<dim3(N >> 5, K >> 5), dim3(256), 0, stream>>>(W, h, l, K, N);
  };
  wsplit(sa_qw, saqh, saql, DD, DD);
  wsplit(sa_kw, sakh, sakl, DD, DD);
  wsplit(sa_vw, savh, savl, DD, DD);
  wsplit(sa_ow, saoh, saol, DD, DD);
  wsplit(ca_qw, caqh, caql, DD, DD);
  wsplit(ca_kw, cakh, cakl, DD, DD);
  wsplit(ca_vw, cavh, cavl, DD, DD);
  wsplit(ca_ow, caoh, caol, DD, DD);
  wsplit(ff_w1, ff1h, ff1l, DD, FFD);
  wsplit(ff_w2, ff2h, ff2l, FFD, DD);

  auto gemmS = [&](const float* A, const _Float16* wh, const _Float16* wl,
                   const float* bi, float* C, int N, int K, int epi, float sc) {
    gemm_mfma<2><<<dim3(N >> 7, 2048 / 64), dim3(256), 0, stream>>>(
        A, wh, wl, bi, C, 2048, N, K, epi, sc);
  };
  auto gemmB = [&](const float* A, const _Float16* wh, const _Float16* wl,
                   const float* bi, float* C, int N, int K, int epi, float sc) {
    gemm_mfma<4><<<dim3(N >> 7, 2048 / 128), dim3(256), 0, stream>>>(
        A, wh, wl, bi, C, 2048, N, K, epi, sc);
  };

  // hoisted: encoder K/V projections
  gemmS(enc, cakh, cakl, ca_kb, ENCK, DD, DD, 0, 1.f);
  gemmS(enc, cavh, cavl, ca_vb, ENCV, DD, DD, 0, 1.f);

  for (int t = 0; t < NHOP; ++t) {
    addcodes_kernel<<<dim3(2048), dim3(256), 0, stream>>>(TIN, TEN, POS, TIM, t,
                                                          (int)nbsd);
    act_kernel<<<dim3(2048), dim3(256), 0, stream>>>(TIN, act_w, act_b, HPp,
                                                     REMp, UWp);
    // self-attention
    gemmS(TIN, saqh, saql, sa_qb, Qf, DD, DD, 1, 0.125f);
    gemmS(TIN, sakh, sakl, sa_kb, Kf, DD, DD, 0, 1.f);
    gemmS(TIN, savh, savl, sa_vb, Vf, DD, DD, 0, 1.f);
    flash_kernel<<<dim3(8, HH, BB), dim3(256), 0, stream>>>(Qf, Kf, Vf, AO,
                                                            nullptr, SS, SS, 1);
    gemmS(AO, saoh, saol, sa_ob, PR, DD, DD, 0, 1.f);
    lnres_kernel<<<dim3(2048), dim3(256), 0, stream>>>(PR, TIN, ln1_g, ln1_b,
                                                       T2);
    // cross-attention
    gemmS(T2, caqh, caql, ca_qb, Qf, DD, DD, 1, 0.125f);
    flash_kernel<<<dim3(8, HH, BB), dim3(256), 0, stream>>>(
        Qf, ENCK, ENCV, AO, encmask, SS, SE, 0);
    gemmS(AO, caoh, caol, ca_ob, PR, DD, DD, 0, 1.f);
    lnres_kernel<<<dim3(2048), dim3(256), 0, stream>>>(PR, T2, ln2_g, ln2_b,
                                                       T3);
    // FFN
    gemmB(T3, ff1h, ff1l, ff_b1, FFH, FFD, DD, 2, 1.f);
    gemmS(FFH, ff2h, ff2l, ff_b2, PR, DD, FFD, 0, 1.f);
    lnres_kernel<<<dim3(2048), dim3(256), 0, stream>>>(PR, T3, ln3_g, ln3_b,
                                                       TEN);
    // prev = tensor*uw + prev*(1-uw)
    prev_kernel<<<dim3(2048), dim3(256), 0, stream>>>(TEN, UWp, out, (int)nbsd);
  }
}

// Round 3
// 3334.965 us; speedup vs baseline: 1.9685x; 1.1074x over previous
//
#include <hip/hip_runtime.h>
#include <math.h>

#define BB 4
#define SS 512
#define SE 512
#define DD 1024
#define HH 16
#define FFD 4096
#define NHOP 6

typedef float f32x4 __attribute__((ext_vector_type(4)));
typedef _Float16 h8 __attribute__((ext_vector_type(8)));

#define GLD16(gp, lp)                                                     \
  __builtin_amdgcn_global_load_lds(                                       \
      (const __attribute__((address_space(1))) void*)(gp),                \
      (__attribute__((address_space(3))) void*)(lp), 16, 0, 0)

// ---------------- block reduction (256 threads = 4 waves) ----------------
__device__ __forceinline__ float blockSum256(float v, float* s4) {
#pragma unroll
  for (int m = 32; m >= 1; m >>= 1) v += __shfl_xor(v, m);
  __syncthreads();
  if ((threadIdx.x & 63) == 0) s4[threadIdx.x >> 6] = v;
  __syncthreads();
  return s4[0] + s4[1] + s4[2] + s4[3];
}

__device__ __forceinline__ void split16(float v, _Float16& h, _Float16& l) {
  h = (_Float16)v;
  l = (_Float16)(v - (float)h);
}

// ---------------- sincos position/time codes (fp64, matches numpy) -------
__global__ void sincos_kernel(float* __restrict__ out, int n) {
  for (int i = blockIdx.x * blockDim.x + threadIdx.x; i < n;
       i += gridDim.x * blockDim.x) {
    int p = i >> 10, d = i & 1023, j = d >> 1;
    double ang = (double)p / pow(10000.0, (2.0 * j) / 1024.0);
    out[i] = (float)((d & 1) ? cos(ang) : sin(ang));
  }
}

// ---------------- embedding gather * sqrt(D) ------------------------------
__global__ void embed_kernel(const int* __restrict__ tok,
                             const float* __restrict__ emb,
                             float* __restrict__ out, int n) {
  for (int i = blockIdx.x * blockDim.x + threadIdx.x; i < n;
       i += gridDim.x * blockDim.x) {
    int row = i >> 10, d = i & 1023;
    out[i] = emb[(size_t)tok[row] * DD + d] * 32.0f;
  }
}

// ---------------- fp32 -> hi/lo fp16 planes (same layout) ----------------
__global__ void asplit_kernel(const float* __restrict__ x,
                              _Float16* __restrict__ h,
                              _Float16* __restrict__ l, int n) {
  for (int i = blockIdx.x * blockDim.x + threadIdx.x; i < n;
       i += gridDim.x * blockDim.x)
    split16(x[i], h[i], l[i]);
}

// ---------------- tensor + pos + time -> TIN planes ----------------------
__global__ void addcodes_kernel(_Float16* __restrict__ th,
                                _Float16* __restrict__ tl,
                                const float* __restrict__ ten,
                                const float* __restrict__ pos,
                                const float* __restrict__ tim, int hop, int n) {
  for (int i = blockIdx.x * blockDim.x + threadIdx.x; i < n;
       i += gridDim.x * blockDim.x) {
    int d = i & 1023, s = (i >> 10) & 511;
    float v = ten[i] + pos[(s << 10) | d] + tim[(hop << 10) | d];
    split16(v, th[i], tl[i]);
  }
}

// ---------------- ACT halting (reads TIN planes) -------------------------
__global__ __launch_bounds__(256)
void act_kernel(const _Float16* __restrict__ th, const _Float16* __restrict__ tl,
                const float* __restrict__ aw, const float* __restrict__ ab,
                float* __restrict__ hp, float* __restrict__ rem,
                float* __restrict__ uw) {
  __shared__ float s4[4];
  int row = blockIdx.x;
  size_t base = (size_t)row * DD;
  float s = 0.f;
#pragma unroll
  for (int k = 0; k < 4; ++k) {
    int d = threadIdx.x + k * 256;
    s += ((float)th[base + d] + (float)tl[base + d]) * aw[d];
  }
  float z = blockSum256(s, s4);
  if (threadIdx.x == 0) {
    z += ab[0];
    float p = 1.0f / (1.0f + expf(-z));
    float h = hp[row], rm = rem[row];
    float s0 = (h < 1.0f) ? 1.0f : 0.0f;
    float cond = h + p * s0;
    float nh = (cond > 0.99f) ? s0 : 0.0f;
    float s1 = (cond <= 0.99f) ? s0 : 0.0f;
    h = h + p * s1;
    rm = rm + nh * (1.0f - h);
    h = h + nh * rm;
    hp[row] = h;
    rem[row] = rm;
    uw[row] = p * s1 + nh * rm;
  }
}

// ---------------- fused residual + LayerNorm -----------------------------
// x = a(fp32) + (rh+rl);  mode 0: fp32 out;  mode 1: planes out
__global__ __launch_bounds__(256)
void lnres_kernel(const float* __restrict__ a, const _Float16* __restrict__ rh,
                  const _Float16* __restrict__ rl, const float* __restrict__ g,
                  const float* __restrict__ be, float* __restrict__ outf,
                  _Float16* __restrict__ oh, _Float16* __restrict__ ol,
                  int mode) {
  __shared__ float s4[4];
  int row = blockIdx.x;
  size_t base = (size_t)row * DD;
  float x[4];
#pragma unroll
  for (int k = 0; k < 4; ++k) {
    size_t idx = base + threadIdx.x + k * 256;
    x[k] = a[idx] + ((float)rh[idx] + (float)rl[idx]);
  }
  float mean = blockSum256(x[0] + x[1] + x[2] + x[3], s4) * (1.0f / 1024.0f);
  float q = 0.f;
#pragma unroll
  for (int k = 0; k < 4; ++k) {
    float dv = x[k] - mean;
    q += dv * dv;
  }
  float var = blockSum256(q, s4) * (1.0f / 1024.0f);
  float inv = 1.0f / sqrtf(var + 1e-12f);
#pragma unroll
  for (int k = 0; k < 4; ++k) {
    int d = threadIdx.x + k * 256;
    size_t idx = base + d;
    float y = (x[k] - mean) * inv * g[d] + be[d];
    if (mode == 0) outf[idx] = y;
    else split16(y, oh[idx], ol[idx]);
  }
}

// ---------------- prev = ten*uw + prev*(1-uw) -----------------------------
__global__ void prev_kernel(const float* __restrict__ ten,
                            const float* __restrict__ uw,
                            float* __restrict__ out, int n) {
  for (int i = blockIdx.x * blockDim.x + threadIdx.x; i < n;
       i += gridDim.x * blockDim.x) {
    float u = uw[i >> 10];
    out[i] = ten[i] * u + out[i] * (1.0f - u);
  }
}

// ---------------- weight transpose + fp16 hi/lo split --------------------
// W[K][N] fp32 -> WhT[N][K], WlT[N][K] fp16
__global__ __launch_bounds__(256)
void wsplit_kernel(const float* __restrict__ W, _Float16* __restrict__ WhT,
                   _Float16* __restrict__ WlT, int K, int N) {
  __shared__ float t[32][33];
  int k0 = blockIdx.y << 5, n0 = blockIdx.x << 5;
  int c = threadIdx.x & 31, r8 = threadIdx.x >> 5;
  for (int rr = r8; rr < 32; rr += 8)
    t[rr][c] = W[(size_t)(k0 + rr) * N + n0 + c];
  __syncthreads();
  for (int rr = r8; rr < 32; rr += 8) {
    float v = t[c][rr];
    split16(v, WhT[(size_t)(n0 + rr) * K + k0 + c],
            WlT[(size_t)(n0 + rr) * K + k0 + c]);
  }
}

// ---------------- concat 3 bias vectors ----------------------------------
__global__ void concat3_kernel(const float* __restrict__ a,
                               const float* __restrict__ b,
                               const float* __restrict__ c,
                               float* __restrict__ o) {
  int i = blockIdx.x * 256 + threadIdx.x;
  if (i < 3072) o[i] = (i < 1024) ? a[i] : ((i < 2048) ? b[i - 1024] : c[i - 2048]);
}

// ---------------- plane-input split-fp16 MFMA GEMM -----------------------
// C[M,N] = (Ah+Al)[M,K] @ (Bh+Bl)^T[N,K] + bias. 64x64 tile, 4 waves 2x2.
// All four planes staged via global_load_lds (16B), XOR slot-swizzle.
// EPI 0: fp32 out. EPI 1: relu -> hi/lo plane out.
template <int EPI>
__global__ __launch_bounds__(256) void gemm_pl(
    const _Float16* __restrict__ Ah, const _Float16* __restrict__ Al,
    const _Float16* __restrict__ Bh, const _Float16* __restrict__ Bl,
    const float* __restrict__ bias, float* __restrict__ Cf,
    _Float16* __restrict__ Ch, _Float16* __restrict__ Cl, int M, int N,
    int K) {
  __shared__ __align__(16) _Float16 sA0[64 * 32], sA1[64 * 32];
  __shared__ __align__(16) _Float16 sB0[64 * 32], sB1[64 * 32];
  const int tid = threadIdx.x;
  const int lane = tid & 63, wid = tid >> 6;
  const int wr = wid >> 1, wc = wid & 1;
  const int m0 = blockIdx.y << 6, n0 = blockIdx.x << 6;
  const int l15 = lane & 15, l4 = lane >> 4;
  // staging: wave wid stages rows 16*wid..16*wid+15 of all 4 planes
  const int lrow = (wid << 4) + (lane >> 2);
  const int ksw = ((lane & 3) ^ ((lrow >> 1) & 3)) << 3;  // swizzled k offset
  const _Float16* gAh = Ah + (size_t)(m0 + lrow) * K + ksw;
  const _Float16* gAl = Al + (size_t)(m0 + lrow) * K + ksw;
  const _Float16* gBh = Bh + (size_t)(n0 + lrow) * K + ksw;
  const _Float16* gBl = Bl + (size_t)(n0 + lrow) * K + ksw;
  _Float16* dA0 = &sA0[wid << 9];
  _Float16* dA1 = &sA1[wid << 9];
  _Float16* dB0 = &sB0[wid << 9];
  _Float16* dB1 = &sB1[wid << 9];
  // fragment read addressing
  const int am[2] = {(wr << 5) + l15, (wr << 5) + 16 + l15};
  const int bn[2] = {(wc << 5) + l15, (wc << 5) + 16 + l15};
  f32x4 acc[2][2];
#pragma unroll
  for (int i = 0; i < 2; ++i)
#pragma unroll
    for (int j = 0; j < 2; ++j) acc[i][j] = (f32x4){0.f, 0.f, 0.f, 0.f};

  const int nk = K >> 5;
  for (int kt = 0; kt < nk; ++kt) {
    const int ko = kt << 5;
    __syncthreads();  // previous iter's LDS reads done
    GLD16(gAh + ko, dA0);
    GLD16(gAl + ko, dA1);
    GLD16(gBh + ko, dB0);
    GLD16(gBl + ko, dB1);
    __syncthreads();  // drains vmcnt -> tiles ready
    h8 a0[2], a1[2], b0[2], b1[2];
#pragma unroll
    for (int f = 0; f < 2; ++f) {
      int m = am[f];
      int st = ((l4 ^ ((m >> 1) & 3)) << 3);
      a0[f] = *(const h8*)&sA0[(m << 5) + st];
      a1[f] = *(const h8*)&sA1[(m << 5) + st];
      int n = bn[f];
      int sn = ((l4 ^ ((n >> 1) & 3)) << 3);
      b0[f] = *(const h8*)&sB0[(n << 5) + sn];
      b1[f] = *(const h8*)&sB1[(n << 5) + sn];
    }
#pragma unroll
    for (int fi = 0; fi < 2; ++fi)
#pragma unroll
      for (int fj = 0; fj < 2; ++fj) {
        acc[fi][fj] = __builtin_amdgcn_mfma_f32_16x16x32_f16(
            a0[fi], b0[fj], acc[fi][fj], 0, 0, 0);
        acc[fi][fj] = __builtin_amdgcn_mfma_f32_16x16x32_f16(
            a1[fi], b0[fj], acc[fi][fj], 0, 0, 0);
        acc[fi][fj] = __builtin_amdgcn_mfma_f32_16x16x32_f16(
            a0[fi], b1[fj], acc[fi][fj], 0, 0, 0);
      }
  }
  // epilogue: C/D layout col=lane&15, row=(lane>>4)*4+r
#pragma unroll
  for (int fi = 0; fi < 2; ++fi) {
    int row = m0 + (wr << 5) + (fi << 4) + (l4 << 2);
#pragma unroll
    for (int fj = 0; fj < 2; ++fj) {
      int col = n0 + (wc << 5) + (fj << 4) + l15;
      float bz = bias[col];
#pragma unroll
      for (int r = 0; r < 4; ++r) {
        float o = acc[fi][fj][r] + bz;
        size_t idx = (size_t)(row + r) * N + col;
        if (EPI == 0) {
          Cf[idx] = o;
        } else {
          o = fmaxf(o, 0.f);
          split16(o, Ch[idx], Cl[idx]);
        }
      }
    }
  }
}

// ---------------- flash attention (fp32, online softmax) -----------------
// strided Q and K/V inputs; scale applied at Q staging; plane output.
__global__ __launch_bounds__(256)
void flash_kernel(const float* __restrict__ Qg, int qs,
                  const float* __restrict__ Kg, const float* __restrict__ Vg,
                  int ks, _Float16* __restrict__ AOh,
                  _Float16* __restrict__ AOl, const int* __restrict__ mask,
                  int Sq, int Sk, int causal, float scale) {
  __shared__ __align__(16) float Qs[64][65];
  __shared__ __align__(16) float Ks[64][65];
  __shared__ __align__(16) float Vs[64][64];
  __shared__ __align__(16) float Ps[64][65];
  __shared__ int Ms[64];
  const int tid = threadIdx.x;
  const int tx = tid & 15, ty = tid >> 4;
  const int qt = blockIdx.x, h = blockIdx.y, b = blockIdx.z;
  const size_t qrow0 = (size_t)b * Sq + (qt << 6);

#pragma unroll
  for (int L = 0; L < 4; ++L) {
    int idx = tid + (L << 8);
    int r = idx >> 4, c4 = idx & 15;
    float4 v = *(const float4*)(Qg + (qrow0 + r) * qs + (h << 6) + (c4 << 2));
    Qs[r][(c4 << 2) + 0] = v.x * scale;
    Qs[r][(c4 << 2) + 1] = v.y * scale;
    Qs[r][(c4 << 2) + 2] = v.z * scale;
    Qs[r][(c4 << 2) + 3] = v.w * scale;
  }
  float m_[4], l_[4], o_[4][4];
#pragma unroll
  for (int i = 0; i < 4; ++i) {
    m_[i] = -3.0e38f;
    l_[i] = 0.f;
#pragma unroll
    for (int j = 0; j < 4; ++j) o_[i][j] = 0.f;
  }
  const int nkt = causal ? (qt + 1) : (Sk >> 6);
  for (int kt = 0; kt < nkt; ++kt) {
    __syncthreads();
    const size_t krow0 = (size_t)b * Sk + (kt << 6);
#pragma unroll
    for (int L = 0; L < 4; ++L) {
      int idx = tid + (L << 8);
      int r = idx >> 4, c4 = idx & 15;
      float4 vk = *(const float4*)(Kg + (krow0 + r) * ks + (h << 6) + (c4 << 2));
      Ks[r][(c4 << 2) + 0] = vk.x;
      Ks[r][(c4 << 2) + 1] = vk.y;
      Ks[r][(c4 << 2) + 2] = vk.z;
      Ks[r][(c4 << 2) + 3] = vk.w;
      float4 vv = *(const float4*)(Vg + (krow0 + r) * ks + (h << 6) + (c4 << 2));
      *(float4*)&Vs[r][c4 << 2] = vv;
    }
    if (mask != nullptr && tid < 64) Ms[tid] = mask[b * Sk + (kt << 6) + tid];
    __syncthreads();
    float s[4][4] = {};
#pragma unroll 8
    for (int d = 0; d < 64; ++d) {
      float a[4], bq[4];
#pragma unroll
      for (int i = 0; i < 4; ++i) a[i] = Qs[(ty << 2) + i][d];
#pragma unroll
      for (int j = 0; j < 4; ++j) bq[j] = Ks[(tx << 2) + j][d];
#pragma unroll
      for (int i = 0; i < 4; ++i)
#pragma unroll
        for (int j = 0; j < 4; ++j) s[i][j] += a[i] * bq[j];
    }
    if (causal && kt == qt) {
#pragma unroll
      for (int i = 0; i < 4; ++i)
#pragma unroll
        for (int j = 0; j < 4; ++j)
          if (((tx << 2) + j) > ((ty << 2) + i)) s[i][j] = -1e20f;
    }
    if (mask != nullptr) {
#pragma unroll
      for (int j = 0; j < 4; ++j)
        if (Ms[(tx << 2) + j] == 0) {
#pragma unroll
          for (int i = 0; i < 4; ++i) s[i][j] = -1e20f;
        }
    }
#pragma unroll
    for (int i = 0; i < 4; ++i) {
      float rmax = fmaxf(fmaxf(s[i][0], s[i][1]), fmaxf(s[i][2], s[i][3]));
#pragma unroll
      for (int mk = 1; mk < 16; mk <<= 1) rmax = fmaxf(rmax, __shfl_xor(rmax, mk));
      float mn = fmaxf(m_[i], rmax);
      float f = expf(m_[i] - mn);
      float pi[4];
      float rs = 0.f;
#pragma unroll
      for (int j = 0; j < 4; ++j) {
        pi[j] = expf(s[i][j] - mn);
        rs += pi[j];
      }
#pragma unroll
      for (int mk = 1; mk < 16; mk <<= 1) rs += __shfl_xor(rs, mk);
      l_[i] = l_[i] * f + rs;
#pragma unroll
      for (int j = 0; j < 4; ++j) o_[i][j] *= f;
      m_[i] = mn;
#pragma unroll
      for (int j = 0; j < 4; ++j) Ps[(ty << 2) + i][(tx << 2) + j] = pi[j];
    }
    __syncthreads();
#pragma unroll 8
    for (int kc = 0; kc < 64; ++kc) {
      float pv[4];
#pragma unroll
      for (int i = 0; i < 4; ++i) pv[i] = Ps[(ty << 2) + i][kc];
      float4 vv = *(const float4*)&Vs[kc][tx << 2];
      float vj[4] = {vv.x, vv.y, vv.z, vv.w};
#pragma unroll
      for (int i = 0; i < 4; ++i)
#pragma unroll
        for (int j = 0; j < 4; ++j) o_[i][j] += pv[i] * vj[j];
    }
  }
#pragma unroll
  for (int i = 0; i < 4; ++i) {
    float inv = 1.0f / l_[i];
    size_t ob = (qrow0 + (ty << 2) + i) * DD + (h << 6) + (tx << 2);
#pragma unroll
    for (int j = 0; j < 4; ++j) {
      float o = o_[i][j] * inv;
      split16(o, AOh[ob + j], AOl[ob + j]);
    }
  }
}

// --------------------------------------------------------------------------
extern "C" void kernel_launch(void* const* d_in, const int* in_sizes, int n_in,
                              void* d_out, int out_size, void* d_ws,
                              size_t ws_size, hipStream_t stream) {
  const int* tokens = (const int*)d_in[0];
  const float* enc = (const float*)d_in[1];
  const int* encmask = (const int*)d_in[2];
  const float* emb = (const float*)d_in[3];
  const float* sa_qw = (const float*)d_in[4];
  const float* sa_qb = (const float*)d_in[5];
  const float* sa_kw = (const float*)d_in[6];
  const float* sa_kb = (const float*)d_in[7];
  const float* sa_vw = (const float*)d_in[8];
  const float* sa_vb = (const float*)d_in[9];
  const float* sa_ow = (const float*)d_in[10];
  const float* sa_ob = (const float*)d_in[11];
  const float* ca_qw = (const float*)d_in[12];
  const float* ca_qb = (const float*)d_in[13];
  const float* ca_kw = (const float*)d_in[14];
  const float* ca_kb = (const float*)d_in[15];
  const float* ca_vw = (const float*)d_in[16];
  const float* ca_vb = (const float*)d_in[17];
  const float* ca_ow = (const float*)d_in[18];
  const float* ca_ob = (const float*)d_in[19];
  const float* ln1_g = (const float*)d_in[20];
  const float* ln1_b = (const float*)d_in[21];
  const float* ln2_g = (const float*)d_in[22];
  const float* ln2_b = (const float*)d_in[23];
  const float* ln3_g = (const float*)d_in[24];
  const float* ln3_b = (const float*)d_in[25];
  const float* ff_w1 = (const float*)d_in[26];
  const float* ff_b1 = (const float*)d_in[27];
  const float* ff_w2 = (const float*)d_in[28];
  const float* ff_b2 = (const float*)d_in[29];
  const float* act_w = (const float*)d_in[30];
  const float* act_b = (const float*)d_in[31];
  float* out = (float*)d_out;

  const size_t nbsd = (size_t)BB * SS * DD;  // 2097152
  const size_t nff = (size_t)BB * SS * FFD;  // 8388608
  const size_t nbs = (size_t)BB * SS;        // 2048
  const size_t wsm = (size_t)DD * DD;        // 1048576
  const size_t wff = (size_t)DD * FFD;       // 4194304

  // ---- fp32 region ----
  float* w = (float*)d_ws;
  float* POS = w;  w += (size_t)SS * DD;
  float* TIM = w;  w += (size_t)NHOP * DD;
  float* TEN = w;  w += nbsd;
  float* PR = w;   w += nbsd;
  float* ENCK = w; w += nbsd;
  float* ENCV = w; w += nbsd;
  float* QKV = w;  w += (size_t)2048 * 3072;  // 6291456
  float* QKVB = w; w += 3072;
  float* HPp = w;  w += nbs;
  float* REMp = w; w += nbs;
  float* UWp = w;  w += nbs;
  // ---- fp16 region ----
  _Float16* hp16 = (_Float16*)w;
  auto halloc = [&](size_t n) { _Float16* r = hp16; hp16 += n; return r; };
  _Float16* TINh = halloc(nbsd); _Float16* TINl = halloc(nbsd);
  _Float16* AOh = halloc(nbsd);  _Float16* AOl = halloc(nbsd);
  _Float16* FFHh = halloc(nff);  _Float16* FFHl = halloc(nff);
  _Float16* qkvWh = halloc(3 * wsm); _Float16* qkvWl = halloc(3 * wsm);
  _Float16* saoWh = halloc(wsm); _Float16* saoWl = halloc(wsm);
  _Float16* caqWh = halloc(wsm); _Float16* caqWl = halloc(wsm);
  _Float16* caoWh = halloc(wsm); _Float16* caoWl = halloc(wsm);
  _Float16* ff1Wh = halloc(wff); _Float16* ff1Wl = halloc(wff);
  _Float16* ff2Wh = halloc(wff); _Float16* ff2Wl = halloc(wff);
  size_t need = (size_t)((char*)hp16 - (char*)d_ws);
  if (ws_size < need) return;

  // aliases (lifetime-disjoint):
  // T3 planes live where TIN planes do (TIN dead after ln1)
  _Float16* T3h = TINh; _Float16* T3l = TINl;
  // T2 planes live in QKV's K-region (dead after self-flash); caq out in Q-region
  _Float16* T2h = (_Float16*)(QKV + nbsd);
  _Float16* T2l = (_Float16*)(QKV + nbsd + nbsd / 2);
  float* CAQ = QKV;
  // enc planes + ca_k/ca_v weight planes live in FFH region (pre-loop only)
  _Float16* ENCsh = FFHh;             _Float16* ENCsl = FFHh + nbsd;
  _Float16* cakWh = FFHh + 2 * nbsd;  _Float16* cakWl = FFHh + 2 * nbsd + wsm;
  _Float16* cavWh = FFHl;             _Float16* cavWl = FFHl + wsm;

  hipMemsetAsync(d_out, 0, nbsd * sizeof(float), stream);
  hipMemsetAsync(HPp, 0, 2 * nbs * sizeof(float), stream);  // hp, rem
  sincos_kernel<<<dim3(512), dim3(256), 0, stream>>>(POS, SS * DD);
  sincos_kernel<<<dim3(24), dim3(256), 0, stream>>>(TIM, NHOP * DD);
  embed_kernel<<<dim3(2048), dim3(256), 0, stream>>>(tokens, emb, TEN, (int)nbsd);
  asplit_kernel<<<dim3(2048), dim3(256), 0, stream>>>(enc, ENCsh, ENCsl,
                                                      (int)nbsd);

  auto wsplit = [&](const float* W, _Float16* h, _Float16* l, int K, int N) {
    wsplit_kernel<<<dim3(N >> 5, K >> 5), dim3(256), 0, stream>>>(W, h, l, K, N);
  };
  wsplit(sa_qw, qkvWh, qkvWl, DD, DD);
  wsplit(sa_kw, qkvWh + wsm, qkvWl + wsm, DD, DD);
  wsplit(sa_vw, qkvWh + 2 * wsm, qkvWl + 2 * wsm, DD, DD);
  wsplit(sa_ow, saoWh, saoWl, DD, DD);
  wsplit(ca_qw, caqWh, caqWl, DD, DD);
  wsplit(ca_kw, cakWh, cakWl, DD, DD);
  wsplit(ca_vw, cavWh, cavWl, DD, DD);
  wsplit(ca_ow, caoWh, caoWl, DD, DD);
  wsplit(ff_w1, ff1Wh, ff1Wl, DD, FFD);
  wsplit(ff_w2, ff2Wh, ff2Wl, FFD, DD);
  concat3_kernel<<<dim3(12), dim3(256), 0, stream>>>(sa_qb, sa_kb, sa_vb, QKVB);

  auto gemmF = [&](const _Float16* ah, const _Float16* al, const _Float16* bh,
                   const _Float16* bl, const float* bi, float* cf, int M, int N,
                   int K) {
    gemm_pl<0><<<dim3(N >> 6, M >> 6), dim3(256), 0, stream>>>(
        ah, al, bh, bl, bi, cf, nullptr, nullptr, M, N, K);
  };
  auto gemmP = [&](const _Float16* ah, const _Float16* al, const _Float16* bh,
                   const _Float16* bl, const float* bi, _Float16* ch,
                   _Float16* cl, int M, int N, int K) {
    gemm_pl<1><<<dim3(N >> 6, M >> 6), dim3(256), 0, stream>>>(
        ah, al, bh, bl, bi, nullptr, ch, cl, M, N, K);
  };

  // hoisted: encoder K/V projections (planes in FFH region are inputs here)
  gemmF(ENCsh, ENCsl, cakWh, cakWl, ca_kb, ENCK, 2048, DD, DD);
  gemmF(ENCsh, ENCsl, cavWh, cavWl, ca_vb, ENCV, 2048, DD, DD);

  for (int t = 0; t < NHOP; ++t) {
    addcodes_kernel<<<dim3(2048), dim3(256), 0, stream>>>(TINh, TINl, TEN, POS,
                                                          TIM, t, (int)nbsd);
    act_kernel<<<dim3(2048), dim3(256), 0, stream>>>(TINh, TINl, act_w, act_b,
                                                     HPp, REMp, UWp);
    // fused QKV projection -> [2048][3072]
    gemmF(TINh, TINl, qkvWh, qkvWl, QKVB, QKV, 2048, 3072, DD);
    flash_kernel<<<dim3(8, HH, BB), dim3(256), 0, stream>>>(
        QKV, 3072, QKV + 1024, QKV + 2048, 3072, AOh, AOl, nullptr, SS, SS, 1,
        0.125f);
    gemmF(AOh, AOl, saoWh, saoWl, sa_ob, PR, 2048, DD, DD);
    lnres_kernel<<<dim3(2048), dim3(256), 0, stream>>>(PR, TINh, TINl, ln1_g,
                                                       ln1_b, nullptr, T2h, T2l,
                                                       1);
    // cross-attention
    gemmF(T2h, T2l, caqWh, caqWl, ca_qb, CAQ, 2048, DD, DD);
    flash_kernel<<<dim3(8, HH, BB), dim3(256), 0, stream>>>(
        CAQ, 1024, ENCK, ENCV, 1024, AOh, AOl, encmask, SS, SE, 0, 0.125f);
    gemmF(AOh, AOl, caoWh, caoWl, ca_ob, PR, 2048, DD, DD);
    lnres_kernel<<<dim3(2048), dim3(256), 0, stream>>>(PR, T2h, T2l, ln2_g,
                                                       ln2_b, nullptr, T3h, T3l,
                                                       1);
    // FFN
    gemmP(T3h, T3l, ff1Wh, ff1Wl, ff_b1, FFHh, FFHl, 2048, FFD, DD);
    gemmF(FFHh, FFHl, ff2Wh, ff2Wl, ff_b2, PR, 2048, DD, FFD);
    lnres_kernel<<<dim3(2048), dim3(256), 0, stream>>>(PR, T3h, T3l, ln3_g,
                                                       ln3_b, TEN, nullptr,
                                                       nullptr, 0);
    // prev = tensor*uw + prev*(1-uw)
    prev_kernel<<<dim3(2048), dim3(256), 0, stream>>>(TEN, UWp, out, (int)nbsd);
  }
}

// Round 4
// 2568.267 us; speedup vs baseline: 2.5562x; 1.2985x over previous
//
#include <hip/hip_runtime.h>
#include <math.h>

#define BB 4
#define SS 512
#define SE 512
#define DD 1024
#define HH 16
#define FFD 4096
#define NHOP 6

typedef float f32x4 __attribute__((ext_vector_type(4)));
typedef _Float16 h8 __attribute__((ext_vector_type(8)));

#define GLD16(gp, lp)                                                     \
  __builtin_amdgcn_global_load_lds(                                       \
      (const __attribute__((address_space(1))) void*)(gp),                \
      (__attribute__((address_space(3))) void*)(lp), 16, 0, 0)

// ---------------- block reduction (256 threads = 4 waves) ----------------
__device__ __forceinline__ float blockSum256(float v, float* s4) {
#pragma unroll
  for (int m = 32; m >= 1; m >>= 1) v += __shfl_xor(v, m);
  __syncthreads();
  if ((threadIdx.x & 63) == 0) s4[threadIdx.x >> 6] = v;
  __syncthreads();
  return s4[0] + s4[1] + s4[2] + s4[3];
}

__device__ __forceinline__ void split16(float v, _Float16& h, _Float16& l) {
  h = (_Float16)v;
  l = (_Float16)(v - (float)h);
}

// swizzled LDS element offset for [64 rows][8 slots of 8 fp16]
__device__ __forceinline__ int swzel(int row, int slot) {
  return (row << 6) + ((slot ^ (row & 7)) << 3);
}

// ---------------- sincos position/time codes (fp64, matches numpy) -------
__global__ void sincos_kernel(float* __restrict__ out, int n) {
  for (int i = blockIdx.x * blockDim.x + threadIdx.x; i < n;
       i += gridDim.x * blockDim.x) {
    int p = i >> 10, d = i & 1023, j = d >> 1;
    double ang = (double)p / pow(10000.0, (2.0 * j) / 1024.0);
    out[i] = (float)((d & 1) ? cos(ang) : sin(ang));
  }
}

// ---------------- embedding gather * sqrt(D) ------------------------------
__global__ void embed_kernel(const int* __restrict__ tok,
                             const float* __restrict__ emb,
                             float* __restrict__ out, int n) {
  for (int i = blockIdx.x * blockDim.x + threadIdx.x; i < n;
       i += gridDim.x * blockDim.x) {
    int row = i >> 10, d = i & 1023;
    out[i] = emb[(size_t)tok[row] * DD + d] * 32.0f;
  }
}

// ---------------- fp32 -> hi/lo fp16 planes (same layout) ----------------
__global__ void asplit_kernel(const float* __restrict__ x,
                              _Float16* __restrict__ h,
                              _Float16* __restrict__ l, int n) {
  for (int i = blockIdx.x * blockDim.x + threadIdx.x; i < n;
       i += gridDim.x * blockDim.x)
    split16(x[i], h[i], l[i]);
}

// ---------------- tensor + pos + time -> TIN planes ----------------------
__global__ void addcodes_kernel(_Float16* __restrict__ th,
                                _Float16* __restrict__ tl,
                                const float* __restrict__ ten,
                                const float* __restrict__ pos,
                                const float* __restrict__ tim, int hop, int n) {
  for (int i = blockIdx.x * blockDim.x + threadIdx.x; i < n;
       i += gridDim.x * blockDim.x) {
    int d = i & 1023, s = (i >> 10) & 511;
    float v = ten[i] + pos[(s << 10) | d] + tim[(hop << 10) | d];
    split16(v, th[i], tl[i]);
  }
}

// ---------------- ACT halting (reads TIN planes) -------------------------
__global__ __launch_bounds__(256)
void act_kernel(const _Float16* __restrict__ th, const _Float16* __restrict__ tl,
                const float* __restrict__ aw, const float* __restrict__ ab,
                float* __restrict__ hp, float* __restrict__ rem,
                float* __restrict__ uw) {
  __shared__ float s4[4];
  int row = blockIdx.x;
  size_t base = (size_t)row * DD;
  float s = 0.f;
#pragma unroll
  for (int k = 0; k < 4; ++k) {
    int d = threadIdx.x + k * 256;
    s += ((float)th[base + d] + (float)tl[base + d]) * aw[d];
  }
  float z = blockSum256(s, s4);
  if (threadIdx.x == 0) {
    z += ab[0];
    float p = 1.0f / (1.0f + expf(-z));
    float h = hp[row], rm = rem[row];
    float s0 = (h < 1.0f) ? 1.0f : 0.0f;
    float cond = h + p * s0;
    float nh = (cond > 0.99f) ? s0 : 0.0f;
    float s1 = (cond <= 0.99f) ? s0 : 0.0f;
    h = h + p * s1;
    rm = rm + nh * (1.0f - h);
    h = h + nh * rm;
    hp[row] = h;
    rem[row] = rm;
    uw[row] = p * s1 + nh * rm;
  }
}

// ---------------- fused residual + LayerNorm -----------------------------
__global__ __launch_bounds__(256)
void lnres_kernel(const float* __restrict__ a, const _Float16* __restrict__ rh,
                  const _Float16* __restrict__ rl, const float* __restrict__ g,
                  const float* __restrict__ be, float* __restrict__ outf,
                  _Float16* __restrict__ oh, _Float16* __restrict__ ol,
                  int mode) {
  __shared__ float s4[4];
  int row = blockIdx.x;
  size_t base = (size_t)row * DD;
  float x[4];
#pragma unroll
  for (int k = 0; k < 4; ++k) {
    size_t idx = base + threadIdx.x + k * 256;
    x[k] = a[idx] + ((float)rh[idx] + (float)rl[idx]);
  }
  float mean = blockSum256(x[0] + x[1] + x[2] + x[3], s4) * (1.0f / 1024.0f);
  float q = 0.f;
#pragma unroll
  for (int k = 0; k < 4; ++k) {
    float dv = x[k] - mean;
    q += dv * dv;
  }
  float var = blockSum256(q, s4) * (1.0f / 1024.0f);
  float inv = 1.0f / sqrtf(var + 1e-12f);
#pragma unroll
  for (int k = 0; k < 4; ++k) {
    int d = threadIdx.x + k * 256;
    size_t idx = base + d;
    float y = (x[k] - mean) * inv * g[d] + be[d];
    if (mode == 0) outf[idx] = y;
    else split16(y, oh[idx], ol[idx]);
  }
}

// ---------------- prev = ten*uw + prev*(1-uw) -----------------------------
__global__ void prev_kernel(const float* __restrict__ ten,
                            const float* __restrict__ uw,
                            float* __restrict__ out, int n) {
  for (int i = blockIdx.x * blockDim.x + threadIdx.x; i < n;
       i += gridDim.x * blockDim.x) {
    float u = uw[i >> 10];
    out[i] = ten[i] * u + out[i] * (1.0f - u);
  }
}

// ---------------- weight transpose + fp16 hi/lo split --------------------
__global__ __launch_bounds__(256)
void wsplit_kernel(const float* __restrict__ W, _Float16* __restrict__ WhT,
                   _Float16* __restrict__ WlT, int K, int N) {
  __shared__ float t[32][33];
  int k0 = blockIdx.y << 5, n0 = blockIdx.x << 5;
  int c = threadIdx.x & 31, r8 = threadIdx.x >> 5;
  for (int rr = r8; rr < 32; rr += 8)
    t[rr][c] = W[(size_t)(k0 + rr) * N + n0 + c];
  __syncthreads();
  for (int rr = r8; rr < 32; rr += 8) {
    float v = t[c][rr];
    split16(v, WhT[(size_t)(n0 + rr) * K + k0 + c],
            WlT[(size_t)(n0 + rr) * K + k0 + c]);
  }
}

// ---------------- concat 3 bias vectors ----------------------------------
__global__ void concat3_kernel(const float* __restrict__ a,
                               const float* __restrict__ b,
                               const float* __restrict__ c,
                               float* __restrict__ o) {
  int i = blockIdx.x * 256 + threadIdx.x;
  if (i < 3072) o[i] = (i < 1024) ? a[i] : ((i < 2048) ? b[i - 1024] : c[i - 2048]);
}

// ---------------- attention prep: scale+split to head-blocked planes -----
// out[((b*H+h)*S + s)*64 + d] = split(src[(b*S+s)*stride + col0 + h*64+d]*sc)
__global__ void prep_sc_kernel(const float* __restrict__ src, int stride,
                               int col0, float scale, _Float16* __restrict__ oh,
                               _Float16* __restrict__ ol) {
  for (int i = blockIdx.x * blockDim.x + threadIdx.x; i < BB * SS * DD;
       i += gridDim.x * blockDim.x) {
    int s = i >> 10, c = i & 1023;
    int b = s >> 9, sr = s & 511, h = c >> 6, d = c & 63;
    float v = src[(size_t)s * stride + col0 + c] * scale;
    size_t o = ((size_t)(b * HH + h) * SS + sr) * 64 + d;
    split16(v, oh[o], ol[o]);
  }
}

// ---------------- attention prep: V transpose to [bh][64][S] planes ------
__global__ __launch_bounds__(256)
void prep_vt_kernel(const float* __restrict__ src, int stride, int col0,
                    _Float16* __restrict__ oh, _Float16* __restrict__ ol) {
  __shared__ float t[64][65];
  int st = blockIdx.x;   // s-tile
  int bh = blockIdx.y;   // 0..63
  int b = bh >> 4, h = bh & 15;
  for (int kidx = threadIdx.x; kidx < 4096; kidx += 256) {
    int r = kidx >> 6, c = kidx & 63;
    t[r][c] = src[(size_t)(b * SS + st * 64 + r) * stride + col0 + h * 64 + c];
  }
  __syncthreads();
  for (int kidx = threadIdx.x; kidx < 4096; kidx += 256) {
    int d = kidx >> 6, s = kidx & 63;
    float v = t[s][d];
    size_t o = ((size_t)bh * 64 + d) * SS + st * 64 + s;
    split16(v, oh[o], ol[o]);
  }
}

// ---------------- plane-input split-fp16 MFMA GEMM -----------------------
template <int EPI>
__global__ __launch_bounds__(256) void gemm_pl(
    const _Float16* __restrict__ Ah, const _Float16* __restrict__ Al,
    const _Float16* __restrict__ Bh, const _Float16* __restrict__ Bl,
    const float* __restrict__ bias, float* __restrict__ Cf,
    _Float16* __restrict__ Ch, _Float16* __restrict__ Cl, int M, int N,
    int K) {
  __shared__ __align__(16) _Float16 sA0[64 * 32], sA1[64 * 32];
  __shared__ __align__(16) _Float16 sB0[64 * 32], sB1[64 * 32];
  const int tid = threadIdx.x;
  const int lane = tid & 63, wid = tid >> 6;
  const int wr = wid >> 1, wc = wid & 1;
  const int m0 = blockIdx.y << 6, n0 = blockIdx.x << 6;
  const int l15 = lane & 15, l4 = lane >> 4;
  const int lrow = (wid << 4) + (lane >> 2);
  const int ksw = ((lane & 3) ^ ((lrow >> 1) & 3)) << 3;
  const _Float16* gAh = Ah + (size_t)(m0 + lrow) * K + ksw;
  const _Float16* gAl = Al + (size_t)(m0 + lrow) * K + ksw;
  const _Float16* gBh = Bh + (size_t)(n0 + lrow) * K + ksw;
  const _Float16* gBl = Bl + (size_t)(n0 + lrow) * K + ksw;
  _Float16* dA0 = &sA0[wid << 9];
  _Float16* dA1 = &sA1[wid << 9];
  _Float16* dB0 = &sB0[wid << 9];
  _Float16* dB1 = &sB1[wid << 9];
  const int am[2] = {(wr << 5) + l15, (wr << 5) + 16 + l15};
  const int bn[2] = {(wc << 5) + l15, (wc << 5) + 16 + l15};
  f32x4 acc[2][2];
#pragma unroll
  for (int i = 0; i < 2; ++i)
#pragma unroll
    for (int j = 0; j < 2; ++j) acc[i][j] = (f32x4){0.f, 0.f, 0.f, 0.f};

  const int nk = K >> 5;
  for (int kt = 0; kt < nk; ++kt) {
    const int ko = kt << 5;
    __syncthreads();
    GLD16(gAh + ko, dA0);
    GLD16(gAl + ko, dA1);
    GLD16(gBh + ko, dB0);
    GLD16(gBl + ko, dB1);
    __syncthreads();
    h8 a0[2], a1[2], b0[2], b1[2];
#pragma unroll
    for (int f = 0; f < 2; ++f) {
      int m = am[f];
      int st = ((l4 ^ ((m >> 1) & 3)) << 3);
      a0[f] = *(const h8*)&sA0[(m << 5) + st];
      a1[f] = *(const h8*)&sA1[(m << 5) + st];
      int n = bn[f];
      int sn = ((l4 ^ ((n >> 1) & 3)) << 3);
      b0[f] = *(const h8*)&sB0[(n << 5) + sn];
      b1[f] = *(const h8*)&sB1[(n << 5) + sn];
    }
#pragma unroll
    for (int fi = 0; fi < 2; ++fi)
#pragma unroll
      for (int fj = 0; fj < 2; ++fj) {
        acc[fi][fj] = __builtin_amdgcn_mfma_f32_16x16x32_f16(
            a0[fi], b0[fj], acc[fi][fj], 0, 0, 0);
        acc[fi][fj] = __builtin_amdgcn_mfma_f32_16x16x32_f16(
            a1[fi], b0[fj], acc[fi][fj], 0, 0, 0);
        acc[fi][fj] = __builtin_amdgcn_mfma_f32_16x16x32_f16(
            a0[fi], b1[fj], acc[fi][fj], 0, 0, 0);
      }
  }
#pragma unroll
  for (int fi = 0; fi < 2; ++fi) {
    int row = m0 + (wr << 5) + (fi << 4) + (l4 << 2);
#pragma unroll
    for (int fj = 0; fj < 2; ++fj) {
      int col = n0 + (wc << 5) + (fj << 4) + l15;
      float bz = bias[col];
#pragma unroll
      for (int r = 0; r < 4; ++r) {
        float o = acc[fi][fj][r] + bz;
        size_t idx = (size_t)(row + r) * N + col;
        if (EPI == 0) {
          Cf[idx] = o;
        } else {
          o = fmaxf(o, 0.f);
          split16(o, Ch[idx], Cl[idx]);
        }
      }
    }
  }
}

// ---------------- MFMA flash attention (split-fp16, online softmax) ------
// Q/K planes [bh][S][64]; Vt planes [bh][64][S]; AO planes [B*S][1024].
// Flat grid 512: bh = x>>3; CAUSAL: qt remapped for load balance.
template <int CAUSAL>
__global__ __launch_bounds__(256) void flash_mfma(
    const _Float16* __restrict__ Qph, const _Float16* __restrict__ Qpl,
    const _Float16* __restrict__ Kph, const _Float16* __restrict__ Kpl,
    const _Float16* __restrict__ Vph, const _Float16* __restrict__ Vpl,
    _Float16* __restrict__ AOh, _Float16* __restrict__ AOl,
    const int* __restrict__ mask, int Sk) {
  __shared__ __align__(16) _Float16 sKh[4096], sKl[4096];
  __shared__ __align__(16) _Float16 sVh[4096], sVl[4096];
  __shared__ __align__(16) _Float16 sPh[4096], sPl[4096];
  __shared__ int Ms[64];
  const int tid = threadIdx.x, lane = tid & 63, wid = tid >> 6;
  const int l15 = lane & 15, l4 = lane >> 4;
  const int flat = blockIdx.x;
  const int bh = flat >> 3, b = bh >> 4;
  int qt = flat & 7;
  if (CAUSAL && (flat >> 8)) qt = 7 - qt;  // complement pairing for balance
  const size_t qkb = (size_t)bh * SS * 64;
  const size_t vtb = (size_t)bh * 64 * Sk;

  // Q fragments (registers, from global; L2-resident)
  h8 aqh[2], aql[2];
#pragma unroll
  for (int ks = 0; ks < 2; ++ks) {
    size_t qa = qkb + (size_t)(qt * 64 + wid * 16 + l15) * 64 + ks * 32 + l4 * 8;
    aqh[ks] = *(const h8*)(Qph + qa);
    aql[ks] = *(const h8*)(Qpl + qa);
  }
  f32x4 o_[4];
  float m_[4], l_[4];
#pragma unroll
  for (int i = 0; i < 4; ++i) o_[i] = (f32x4){0.f, 0.f, 0.f, 0.f};
#pragma unroll
  for (int r = 0; r < 4; ++r) { m_[r] = -3.0e38f; l_[r] = 0.f; }

  const int nkt = CAUSAL ? (qt + 1) : (Sk >> 6);
  for (int kt = 0; kt < nkt; ++kt) {
    __syncthreads();  // prev iter LDS reads done
#pragma unroll
    for (int c = 0; c < 2; ++c) {
      int u = (c << 8) + tid;
      int row = u >> 3, lg = (u & 7) ^ (row & 7);
      int de = (c << 11) + (wid << 9);  // dest elem base (wave-uniform)
      size_t ksrc = qkb + (size_t)(kt * 64 + row) * 64 + lg * 8;
      size_t vsrc = vtb + (size_t)row * Sk + kt * 64 + lg * 8;
      GLD16(Kph + ksrc, &sKh[de]);
      GLD16(Kpl + ksrc, &sKl[de]);
      GLD16(Vph + vsrc, &sVh[de]);
      GLD16(Vpl + vsrc, &sVl[de]);
    }
    if (mask != nullptr && tid < 64) Ms[tid] = mask[b * Sk + kt * 64 + tid];
    __syncthreads();  // tiles ready
    // QK^T (3-product split)
    f32x4 sc[4];
#pragma unroll
    for (int fj = 0; fj < 4; ++fj) {
      sc[fj] = (f32x4){0.f, 0.f, 0.f, 0.f};
#pragma unroll
      for (int ks = 0; ks < 2; ++ks) {
        int off = swzel(fj * 16 + l15, ks * 4 + l4);
        h8 bkh = *(const h8*)&sKh[off];
        h8 bkl = *(const h8*)&sKl[off];
        sc[fj] = __builtin_amdgcn_mfma_f32_16x16x32_f16(aqh[ks], bkh, sc[fj], 0, 0, 0);
        sc[fj] = __builtin_amdgcn_mfma_f32_16x16x32_f16(aql[ks], bkh, sc[fj], 0, 0, 0);
        sc[fj] = __builtin_amdgcn_mfma_f32_16x16x32_f16(aqh[ks], bkl, sc[fj], 0, 0, 0);
      }
    }
    if (CAUSAL && kt == qt) {
#pragma unroll
      for (int fj = 0; fj < 4; ++fj)
#pragma unroll
        for (int r = 0; r < 4; ++r)
          if (fj * 16 + l15 > wid * 16 + l4 * 4 + r) sc[fj][r] = -1e20f;
    }
    if (mask != nullptr) {
#pragma unroll
      for (int fj = 0; fj < 4; ++fj)
        if (Ms[fj * 16 + l15] == 0) {
#pragma unroll
          for (int r = 0; r < 4; ++r) sc[fj][r] = -1e20f;
        }
    }
    // online softmax rows; write P planes (own rows only -> no barrier)
#pragma unroll
    for (int r = 0; r < 4; ++r) {
      float rm = fmaxf(fmaxf(sc[0][r], sc[1][r]), fmaxf(sc[2][r], sc[3][r]));
#pragma unroll
      for (int mk = 1; mk < 16; mk <<= 1) rm = fmaxf(rm, __shfl_xor(rm, mk));
      float mn = fmaxf(m_[r], rm);
      float f = __expf(m_[r] - mn);
      float rs = 0.f;
      int prow = wid * 16 + l4 * 4 + r;
#pragma unroll
      for (int fj = 0; fj < 4; ++fj) {
        float p = __expf(sc[fj][r] - mn);
        rs += p;
        int col = fj * 16 + l15;
        int el = (prow << 6) + ((((col >> 3) ^ (prow & 7))) << 3) + (col & 7);
        _Float16 ph = (_Float16)p;
        sPh[el] = ph;
        sPl[el] = (_Float16)(p - (float)ph);
      }
#pragma unroll
      for (int mk = 1; mk < 16; mk <<= 1) rs += __shfl_xor(rs, mk);
      l_[r] = l_[r] * f + rs;
      m_[r] = mn;
#pragma unroll
      for (int df = 0; df < 4; ++df) o_[df][r] *= f;
    }
    // PV (3-product split)
#pragma unroll
    for (int ks = 0; ks < 2; ++ks) {
      int poff = swzel(wid * 16 + l15, ks * 4 + l4);
      h8 aph = *(const h8*)&sPh[poff];
      h8 apl = *(const h8*)&sPl[poff];
#pragma unroll
      for (int df = 0; df < 4; ++df) {
        int voff = swzel(df * 16 + l15, ks * 4 + l4);
        h8 bvh = *(const h8*)&sVh[voff];
        h8 bvl = *(const h8*)&sVl[voff];
        o_[df] = __builtin_amdgcn_mfma_f32_16x16x32_f16(aph, bvh, o_[df], 0, 0, 0);
        o_[df] = __builtin_amdgcn_mfma_f32_16x16x32_f16(apl, bvh, o_[df], 0, 0, 0);
        o_[df] = __builtin_amdgcn_mfma_f32_16x16x32_f16(aph, bvl, o_[df], 0, 0, 0);
      }
    }
  }
  // epilogue -> AO planes [B*S][1024]
#pragma unroll
  for (int r = 0; r < 4; ++r) {
    float inv = 1.0f / l_[r];
    int row = qt * 64 + wid * 16 + l4 * 4 + r;
    size_t ob = ((size_t)b * SS + row) * DD + (bh & 15) * 64;
#pragma unroll
    for (int df = 0; df < 4; ++df) {
      float o = o_[df][r] * inv;
      split16(o, AOh[ob + df * 16 + l15], AOl[ob + df * 16 + l15]);
    }
  }
}

// --------------------------------------------------------------------------
extern "C" void kernel_launch(void* const* d_in, const int* in_sizes, int n_in,
                              void* d_out, int out_size, void* d_ws,
                              size_t ws_size, hipStream_t stream) {
  const int* tokens = (const int*)d_in[0];
  const float* enc = (const float*)d_in[1];
  const int* encmask = (const int*)d_in[2];
  const float* emb = (const float*)d_in[3];
  const float* sa_qw = (const float*)d_in[4];
  const float* sa_qb = (const float*)d_in[5];
  const float* sa_kw = (const float*)d_in[6];
  const float* sa_kb = (const float*)d_in[7];
  const float* sa_vw = (const float*)d_in[8];
  const float* sa_vb = (const float*)d_in[9];
  const float* sa_ow = (const float*)d_in[10];
  const float* sa_ob = (const float*)d_in[11];
  const float* ca_qw = (const float*)d_in[12];
  const float* ca_qb = (const float*)d_in[13];
  const float* ca_kw = (const float*)d_in[14];
  const float* ca_kb = (const float*)d_in[15];
  const float* ca_vw = (const float*)d_in[16];
  const float* ca_vb = (const float*)d_in[17];
  const float* ca_ow = (const float*)d_in[18];
  const float* ca_ob = (const float*)d_in[19];
  const float* ln1_g = (const float*)d_in[20];
  const float* ln1_b = (const float*)d_in[21];
  const float* ln2_g = (const float*)d_in[22];
  const float* ln2_b = (const float*)d_in[23];
  const float* ln3_g = (const float*)d_in[24];
  const float* ln3_b = (const float*)d_in[25];
  const float* ff_w1 = (const float*)d_in[26];
  const float* ff_b1 = (const float*)d_in[27];
  const float* ff_w2 = (const float*)d_in[28];
  const float* ff_b2 = (const float*)d_in[29];
  const float* act_w = (const float*)d_in[30];
  const float* act_b = (const float*)d_in[31];
  float* out = (float*)d_out;

  const size_t nbsd = (size_t)BB * SS * DD;  // 2097152
  const size_t nff = (size_t)BB * SS * FFD;  // 8388608
  const size_t nbs = (size_t)BB * SS;        // 2048
  const size_t wsm = (size_t)DD * DD;
  const size_t wff = (size_t)DD * FFD;

  // ---- fp32 region ----
  float* w = (float*)d_ws;
  float* POS = w;  w += (size_t)SS * DD;
  float* TIM = w;  w += (size_t)NHOP * DD;
  float* TEN = w;  w += nbsd;
  float* PR = w;   w += nbsd;
  float* ENCK = w; w += nbsd;
  float* ENCV = w; w += nbsd;
  float* QKV = w;  w += (size_t)2048 * 3072;
  float* QKVB = w; w += 3072;
  float* HPp = w;  w += nbs;
  float* REMp = w; w += nbs;
  float* UWp = w;  w += nbs;
  // ---- fp16 region ----
  _Float16* hp16 = (_Float16*)w;
  auto halloc = [&](size_t n) { _Float16* r = hp16; hp16 += n; return r; };
  _Float16* TINh = halloc(nbsd); _Float16* TINl = halloc(nbsd);
  _Float16* AOh = halloc(nbsd);  _Float16* AOl = halloc(nbsd);
  _Float16* FFHh = halloc(nff);  _Float16* FFHl = halloc(nff);
  _Float16* qkvWh = halloc(3 * wsm); _Float16* qkvWl = halloc(3 * wsm);
  _Float16* saoWh = halloc(wsm); _Float16* saoWl = halloc(wsm);
  _Float16* caqWh = halloc(wsm); _Float16* caqWl = halloc(wsm);
  _Float16* caoWh = halloc(wsm); _Float16* caoWl = halloc(wsm);
  _Float16* ff1Wh = halloc(wff); _Float16* ff1Wl = halloc(wff);
  _Float16* ff2Wh = halloc(wff); _Float16* ff2Wl = halloc(wff);
  // encoder K/V attention planes (persist whole launch)
  _Float16* EKh = halloc(nbsd); _Float16* EKl = halloc(nbsd);
  _Float16* EVh = halloc(nbsd); _Float16* EVl = halloc(nbsd);
  size_t need = (size_t)((char*)hp16 - (char*)d_ws);
  if (ws_size < need) return;

  // lifetime-disjoint aliases:
  _Float16* T3h = TINh; _Float16* T3l = TINl;          // after ln2
  _Float16* T2h = (_Float16*)(QKV + nbsd);             // QKV K-region, after preps
  _Float16* T2l = (_Float16*)(QKV + nbsd + nbsd / 2);
  float* CAQ = QKV;                                    // QKV Q-region
  // self-attn + cross-Q planes alias FFH (dead during attention phase)
  _Float16* Qph = FFHh;             _Float16* Qpl = FFHh + nbsd;
  _Float16* Kph = FFHh + 2 * nbsd;  _Float16* Kpl = FFHh + 3 * nbsd;
  _Float16* Vph = FFHl;             _Float16* Vpl = FFHl + nbsd;
  _Float16* CQh = FFHl + 2 * nbsd;  _Float16* CQl = FFHl + 3 * nbsd;

  hipMemsetAsync(d_out, 0, nbsd * sizeof(float), stream);
  hipMemsetAsync(HPp, 0, 2 * nbs * sizeof(float), stream);
  sincos_kernel<<<dim3(512), dim3(256), 0, stream>>>(POS, SS * DD);
  sincos_kernel<<<dim3(24), dim3(256), 0, stream>>>(TIM, NHOP * DD);
  embed_kernel<<<dim3(2048), dim3(256), 0, stream>>>(tokens, emb, TEN, (int)nbsd);
  asplit_kernel<<<dim3(2048), dim3(256), 0, stream>>>(enc, TINh, TINl, (int)nbsd);

  auto wsplit = [&](const float* W, _Float16* h, _Float16* l, int K, int N) {
    wsplit_kernel<<<dim3(N >> 5, K >> 5), dim3(256), 0, stream>>>(W, h, l, K, N);
  };
  wsplit(sa_qw, qkvWh, qkvWl, DD, DD);
  wsplit(sa_kw, qkvWh + wsm, qkvWl + wsm, DD, DD);
  wsplit(sa_vw, qkvWh + 2 * wsm, qkvWl + 2 * wsm, DD, DD);
  wsplit(sa_ow, saoWh, saoWl, DD, DD);
  wsplit(ca_qw, caqWh, caqWl, DD, DD);
  wsplit(ca_kw, FFHh, FFHh + wsm, DD, DD);        // temp in FFH
  wsplit(ca_vw, FFHh + 2 * wsm, FFHh + 3 * wsm, DD, DD);
  wsplit(ca_ow, caoWh, caoWl, DD, DD);
  wsplit(ff_w1, ff1Wh, ff1Wl, DD, FFD);
  wsplit(ff_w2, ff2Wh, ff2Wl, FFD, DD);
  concat3_kernel<<<dim3(12), dim3(256), 0, stream>>>(sa_qb, sa_kb, sa_vb, QKVB);

  auto gemmF = [&](const _Float16* ah, const _Float16* al, const _Float16* bh,
                   const _Float16* bl, const float* bi, float* cf, int M, int N,
                   int K) {
    gemm_pl<0><<<dim3(N >> 6, M >> 6), dim3(256), 0, stream>>>(
        ah, al, bh, bl, bi, cf, nullptr, nullptr, M, N, K);
  };
  auto gemmP = [&](const _Float16* ah, const _Float16* al, const _Float16* bh,
                   const _Float16* bl, const float* bi, _Float16* ch,
                   _Float16* cl, int M, int N, int K) {
    gemm_pl<1><<<dim3(N >> 6, M >> 6), dim3(256), 0, stream>>>(
        ah, al, bh, bl, bi, nullptr, ch, cl, M, N, K);
  };

  // hoisted: encoder K/V projections -> fp32, then attention planes
  gemmF(TINh, TINl, FFHh, FFHh + wsm, ca_kb, ENCK, 2048, DD, DD);
  gemmF(TINh, TINl, FFHh + 2 * wsm, FFHh + 3 * wsm, ca_vb, ENCV, 2048, DD, DD);
  prep_sc_kernel<<<dim3(2048), dim3(256), 0, stream>>>(ENCK, DD, 0, 1.f, EKh, EKl);
  prep_vt_kernel<<<dim3(8, 64), dim3(256), 0, stream>>>(ENCV, DD, 0, EVh, EVl);

  for (int t = 0; t < NHOP; ++t) {
    addcodes_kernel<<<dim3(2048), dim3(256), 0, stream>>>(TINh, TINl, TEN, POS,
                                                          TIM, t, (int)nbsd);
    act_kernel<<<dim3(2048), dim3(256), 0, stream>>>(TINh, TINl, act_w, act_b,
                                                     HPp, REMp, UWp);
    // fused QKV projection -> fp32 [2048][3072]
    gemmF(TINh, TINl, qkvWh, qkvWl, QKVB, QKV, 2048, 3072, DD);
    // attention planes
    prep_sc_kernel<<<dim3(2048), dim3(256), 0, stream>>>(QKV, 3072, 0, 0.125f,
                                                         Qph, Qpl);
    prep_sc_kernel<<<dim3(2048), dim3(256), 0, stream>>>(QKV, 3072, 1024, 1.f,
                                                         Kph, Kpl);
    prep_vt_kernel<<<dim3(8, 64), dim3(256), 0, stream>>>(QKV, 3072, 2048, Vph,
                                                          Vpl);
    flash_mfma<1><<<dim3(512), dim3(256), 0, stream>>>(
        Qph, Qpl, Kph, Kpl, Vph, Vpl, AOh, AOl, nullptr, SS);
    gemmF(AOh, AOl, saoWh, saoWl, sa_ob, PR, 2048, DD, DD);
    lnres_kernel<<<dim3(2048), dim3(256), 0, stream>>>(PR, TINh, TINl, ln1_g,
                                                       ln1_b, nullptr, T2h, T2l, 1);
    // cross-attention
    gemmF(T2h, T2l, caqWh, caqWl, ca_qb, CAQ, 2048, DD, DD);
    prep_sc_kernel<<<dim3(2048), dim3(256), 0, stream>>>(CAQ, DD, 0, 0.125f,
                                                         CQh, CQl);
    flash_mfma<0><<<dim3(512), dim3(256), 0, stream>>>(
        CQh, CQl, EKh, EKl, EVh, EVl, AOh, AOl, encmask, SE);
    gemmF(AOh, AOl, caoWh, caoWl, ca_ob, PR, 2048, DD, DD);
    lnres_kernel<<<dim3(2048), dim3(256), 0, stream>>>(PR, T2h, T2l, ln2_g,
                                                       ln2_b, nullptr, T3h, T3l, 1);
    // FFN
    gemmP(T3h, T3l, ff1Wh, ff1Wl, ff_b1, FFHh, FFHl, 2048, FFD, DD);
    gemmF(FFHh, FFHl, ff2Wh, ff2Wl, ff_b2, PR, 2048, DD, FFD);
    lnres_kernel<<<dim3(2048), dim3(256), 0, stream>>>(PR, T3h, T3l, ln3_g,
                                                       ln3_b, TEN, nullptr,
                                                       nullptr, 0);
    prev_kernel<<<dim3(2048), dim3(256), 0, stream>>>(TEN, UWp, out, (int)nbsd);
  }
}

// Round 5
// 2368.816 us; speedup vs baseline: 2.7714x; 1.0842x over previous
//
#include <hip/hip_runtime.h>
#include <math.h>

#define BB 4
#define SS 512
#define SE 512
#define DD 1024
#define HH 16
#define FFD 4096
#define NHOP 6

typedef float f32x4 __attribute__((ext_vector_type(4)));
typedef _Float16 h8 __attribute__((ext_vector_type(8)));

#define GLD16(gp, lp)                                                     \
  __builtin_amdgcn_global_load_lds(                                       \
      (const __attribute__((address_space(1))) void*)(gp),                \
      (__attribute__((address_space(3))) void*)(lp), 16, 0, 0)

// ---------------- block reduction (256 threads = 4 waves) ----------------
__device__ __forceinline__ float blockSum256(float v, float* s4) {
#pragma unroll
  for (int m = 32; m >= 1; m >>= 1) v += __shfl_xor(v, m);
  __syncthreads();
  if ((threadIdx.x & 63) == 0) s4[threadIdx.x >> 6] = v;
  __syncthreads();
  return s4[0] + s4[1] + s4[2] + s4[3];
}

__device__ __forceinline__ void split16(float v, _Float16& h, _Float16& l) {
  h = (_Float16)v;
  l = (_Float16)(v - (float)h);
}

// swizzled LDS element offset for [64 rows][8 slots of 8 fp16]
__device__ __forceinline__ int swzel(int row, int slot) {
  return (row << 6) + ((slot ^ (row & 7)) << 3);
}

// ---------------- sincos position/time codes (fp64, matches numpy) -------
__global__ void sincos_kernel(float* __restrict__ out, int n) {
  for (int i = blockIdx.x * blockDim.x + threadIdx.x; i < n;
       i += gridDim.x * blockDim.x) {
    int p = i >> 10, d = i & 1023, j = d >> 1;
    double ang = (double)p / pow(10000.0, (2.0 * j) / 1024.0);
    out[i] = (float)((d & 1) ? cos(ang) : sin(ang));
  }
}

// ---------------- embedding gather * sqrt(D) ------------------------------
__global__ void embed_kernel(const int* __restrict__ tok,
                             const float* __restrict__ emb,
                             float* __restrict__ out, int n) {
  for (int i = blockIdx.x * blockDim.x + threadIdx.x; i < n;
       i += gridDim.x * blockDim.x) {
    int row = i >> 10, d = i & 1023;
    out[i] = emb[(size_t)tok[row] * DD + d] * 32.0f;
  }
}

// ---------------- fp32 -> hi/lo fp16 planes (same layout) ----------------
__global__ void asplit_kernel(const float* __restrict__ x,
                              _Float16* __restrict__ h,
                              _Float16* __restrict__ l, int n) {
  for (int i = blockIdx.x * blockDim.x + threadIdx.x; i < n;
       i += gridDim.x * blockDim.x)
    split16(x[i], h[i], l[i]);
}

// ---------------- tensor + pos + time -> TIN planes ----------------------
__global__ void addcodes_kernel(_Float16* __restrict__ th,
                                _Float16* __restrict__ tl,
                                const float* __restrict__ ten,
                                const float* __restrict__ pos,
                                const float* __restrict__ tim, int hop, int n) {
  for (int i = blockIdx.x * blockDim.x + threadIdx.x; i < n;
       i += gridDim.x * blockDim.x) {
    int d = i & 1023, s = (i >> 10) & 511;
    float v = ten[i] + pos[(s << 10) | d] + tim[(hop << 10) | d];
    split16(v, th[i], tl[i]);
  }
}

// ---------------- ACT halting (reads TIN planes) -------------------------
__global__ __launch_bounds__(256)
void act_kernel(const _Float16* __restrict__ th, const _Float16* __restrict__ tl,
                const float* __restrict__ aw, const float* __restrict__ ab,
                float* __restrict__ hp, float* __restrict__ rem,
                float* __restrict__ uw) {
  __shared__ float s4[4];
  int row = blockIdx.x;
  size_t base = (size_t)row * DD;
  float s = 0.f;
#pragma unroll
  for (int k = 0; k < 4; ++k) {
    int d = threadIdx.x + k * 256;
    s += ((float)th[base + d] + (float)tl[base + d]) * aw[d];
  }
  float z = blockSum256(s, s4);
  if (threadIdx.x == 0) {
    z += ab[0];
    float p = 1.0f / (1.0f + expf(-z));
    float h = hp[row], rm = rem[row];
    float s0 = (h < 1.0f) ? 1.0f : 0.0f;
    float cond = h + p * s0;
    float nh = (cond > 0.99f) ? s0 : 0.0f;
    float s1 = (cond <= 0.99f) ? s0 : 0.0f;
    h = h + p * s1;
    rm = rm + nh * (1.0f - h);
    h = h + nh * rm;
    hp[row] = h;
    rem[row] = rm;
    uw[row] = p * s1 + nh * rm;
  }
}

// ---------------- fused residual + LayerNorm (+ optional prev update) ----
__global__ __launch_bounds__(256)
void lnres_kernel(const float* __restrict__ a, const _Float16* __restrict__ rh,
                  const _Float16* __restrict__ rl, const float* __restrict__ g,
                  const float* __restrict__ be, float* __restrict__ outf,
                  _Float16* __restrict__ oh, _Float16* __restrict__ ol,
                  const float* __restrict__ uwv, float* __restrict__ po,
                  int mode) {
  __shared__ float s4[4];
  int row = blockIdx.x;
  size_t base = (size_t)row * DD;
  float x[4];
#pragma unroll
  for (int k = 0; k < 4; ++k) {
    size_t idx = base + threadIdx.x + k * 256;
    x[k] = a[idx] + ((float)rh[idx] + (float)rl[idx]);
  }
  float mean = blockSum256(x[0] + x[1] + x[2] + x[3], s4) * (1.0f / 1024.0f);
  float q = 0.f;
#pragma unroll
  for (int k = 0; k < 4; ++k) {
    float dv = x[k] - mean;
    q += dv * dv;
  }
  float var = blockSum256(q, s4) * (1.0f / 1024.0f);
  float inv = 1.0f / sqrtf(var + 1e-12f);
  float u = (mode == 0) ? uwv[row] : 0.f;
#pragma unroll
  for (int k = 0; k < 4; ++k) {
    int d = threadIdx.x + k * 256;
    size_t idx = base + d;
    float y = (x[k] - mean) * inv * g[d] + be[d];
    if (mode == 0) {
      outf[idx] = y;
      po[idx] = y * u + po[idx] * (1.0f - u);  // prev update fused
    } else {
      split16(y, oh[idx], ol[idx]);
    }
  }
}

// ---------------- weight transpose + fp16 hi/lo split --------------------
__global__ __launch_bounds__(256)
void wsplit_kernel(const float* __restrict__ W, _Float16* __restrict__ WhT,
                   _Float16* __restrict__ WlT, int K, int N) {
  __shared__ float t[32][33];
  int k0 = blockIdx.y << 5, n0 = blockIdx.x << 5;
  int c = threadIdx.x & 31, r8 = threadIdx.x >> 5;
  for (int rr = r8; rr < 32; rr += 8)
    t[rr][c] = W[(size_t)(k0 + rr) * N + n0 + c];
  __syncthreads();
  for (int rr = r8; rr < 32; rr += 8) {
    float v = t[c][rr];
    split16(v, WhT[(size_t)(n0 + rr) * K + k0 + c],
            WlT[(size_t)(n0 + rr) * K + k0 + c]);
  }
}

// ---------------- concat 3 bias vectors ----------------------------------
__global__ void concat3_kernel(const float* __restrict__ a,
                               const float* __restrict__ b,
                               const float* __restrict__ c,
                               float* __restrict__ o) {
  int i = blockIdx.x * 256 + threadIdx.x;
  if (i < 3072) o[i] = (i < 1024) ? a[i] : ((i < 2048) ? b[i - 1024] : c[i - 2048]);
}

// ---------------- V transpose to [bh][64][S] planes ----------------------
__global__ __launch_bounds__(256)
void prep_vt_kernel(const float* __restrict__ src, int stride, int col0,
                    _Float16* __restrict__ oh, _Float16* __restrict__ ol) {
  __shared__ float t[64][65];
  int st = blockIdx.x;   // s-tile
  int bh = blockIdx.y;   // 0..63
  int b = bh >> 4, h = bh & 15;
  for (int kidx = threadIdx.x; kidx < 4096; kidx += 256) {
    int r = kidx >> 6, c = kidx & 63;
    t[r][c] = src[(size_t)(b * SS + st * 64 + r) * stride + col0 + h * 64 + c];
  }
  __syncthreads();
  for (int kidx = threadIdx.x; kidx < 4096; kidx += 256) {
    int d = kidx >> 6, s = kidx & 63;
    float v = t[s][d];
    size_t o = ((size_t)bh * 64 + d) * SS + st * 64 + s;
    split16(v, oh[o], ol[o]);
  }
}

// ---------------- plane-input split-fp16 MFMA GEMM (2-phase pipeline) ----
// C[M,N] = (Ah+Al)[M,K] @ (Bh+Bl)^T[N,K] + bias. 64x64 tile, 4 waves 2x2.
// Double-buffered LDS; stage(t+1) issued before compute(t); ONE barrier/step.
// EPI 0: fp32 out. EPI 1: relu -> planes. EPI 2: QKV dispatch (Q/K planes +
// V fp32). EPI 3: head-blocked planes with runtime scale.
template <int EPI>
__global__ __launch_bounds__(256) void gemm_pl(
    const _Float16* __restrict__ Ah, const _Float16* __restrict__ Al,
    const _Float16* __restrict__ Bh, const _Float16* __restrict__ Bl,
    const float* __restrict__ bias, float* __restrict__ Cf,
    _Float16* __restrict__ Ch, _Float16* __restrict__ Cl,
    _Float16* __restrict__ Ch2, _Float16* __restrict__ Cl2, int M, int N,
    int K, float scale) {
  __shared__ __align__(16) _Float16 sA0[2][2048], sA1[2][2048];
  __shared__ __align__(16) _Float16 sB0[2][2048], sB1[2][2048];
  const int tid = threadIdx.x;
  const int lane = tid & 63, wid = tid >> 6;
  const int wr = wid >> 1, wc = wid & 1;
  const int m0 = blockIdx.y << 6, n0 = blockIdx.x << 6;
  const int l15 = lane & 15, l4 = lane >> 4;
  const int lrow = (wid << 4) + (lane >> 2);
  const int ksw = ((lane & 3) ^ ((lrow >> 1) & 3)) << 3;
  const _Float16* gAh = Ah + (size_t)(m0 + lrow) * K + ksw;
  const _Float16* gAl = Al + (size_t)(m0 + lrow) * K + ksw;
  const _Float16* gBh = Bh + (size_t)(n0 + lrow) * K + ksw;
  const _Float16* gBl = Bl + (size_t)(n0 + lrow) * K + ksw;
  const int dbase = wid << 9;
  const int am[2] = {(wr << 5) + l15, (wr << 5) + 16 + l15};
  const int bn[2] = {(wc << 5) + l15, (wc << 5) + 16 + l15};
  f32x4 acc[2][2];
#pragma unroll
  for (int i = 0; i < 2; ++i)
#pragma unroll
    for (int j = 0; j < 2; ++j) acc[i][j] = (f32x4){0.f, 0.f, 0.f, 0.f};

  const int nk = K >> 5;
  // prologue: stage tile 0 into buf 0
  GLD16(gAh, &sA0[0][dbase]);
  GLD16(gAl, &sA1[0][dbase]);
  GLD16(gBh, &sB0[0][dbase]);
  GLD16(gBl, &sB1[0][dbase]);
  __syncthreads();
  int cur = 0;
  for (int kt = 0; kt < nk; ++kt) {
    // issue next-tile stage BEFORE compute (latency hides under MFMA/ds_read)
    if (kt + 1 < nk) {
      const int ko = (kt + 1) << 5;
      GLD16(gAh + ko, &sA0[cur ^ 1][dbase]);
      GLD16(gAl + ko, &sA1[cur ^ 1][dbase]);
      GLD16(gBh + ko, &sB0[cur ^ 1][dbase]);
      GLD16(gBl + ko, &sB1[cur ^ 1][dbase]);
    }
    const _Float16* pA0 = sA0[cur];
    const _Float16* pA1 = sA1[cur];
    const _Float16* pB0 = sB0[cur];
    const _Float16* pB1 = sB1[cur];
    h8 a0[2], a1[2], b0[2], b1[2];
#pragma unroll
    for (int f = 0; f < 2; ++f) {
      int m = am[f];
      int st = ((l4 ^ ((m >> 1) & 3)) << 3);
      a0[f] = *(const h8*)&pA0[(m << 5) + st];
      a1[f] = *(const h8*)&pA1[(m << 5) + st];
      int n = bn[f];
      int sn = ((l4 ^ ((n >> 1) & 3)) << 3);
      b0[f] = *(const h8*)&pB0[(n << 5) + sn];
      b1[f] = *(const h8*)&pB1[(n << 5) + sn];
    }
#pragma unroll
    for (int fi = 0; fi < 2; ++fi)
#pragma unroll
      for (int fj = 0; fj < 2; ++fj) {
        acc[fi][fj] = __builtin_amdgcn_mfma_f32_16x16x32_f16(
            a0[fi], b0[fj], acc[fi][fj], 0, 0, 0);
        acc[fi][fj] = __builtin_amdgcn_mfma_f32_16x16x32_f16(
            a1[fi], b0[fj], acc[fi][fj], 0, 0, 0);
        acc[fi][fj] = __builtin_amdgcn_mfma_f32_16x16x32_f16(
            a0[fi], b1[fj], acc[fi][fj], 0, 0, 0);
      }
    __syncthreads();  // drains prefetch (vmcnt) + guards buffer reuse
    cur ^= 1;
  }
  // epilogue: C/D layout col=lane&15, row=(lane>>4)*4+r
#pragma unroll
  for (int fi = 0; fi < 2; ++fi) {
    int row = m0 + (wr << 5) + (fi << 4) + (l4 << 2);
#pragma unroll
    for (int fj = 0; fj < 2; ++fj) {
      int col = n0 + (wc << 5) + (fj << 4) + l15;
      float bz = bias[col];
#pragma unroll
      for (int r = 0; r < 4; ++r) {
        float o = acc[fi][fj][r] + bz;
        int rowr = row + r;
        if (EPI == 0) {
          Cf[(size_t)rowr * N + col] = o;
        } else if (EPI == 1) {
          o = fmaxf(o, 0.f);
          size_t idx = (size_t)rowr * N + col;
          split16(o, Ch[idx], Cl[idx]);
        } else if (EPI == 3) {
          o *= scale;
          int b = rowr >> 9, sr = rowr & 511, h = col >> 6, d = col & 63;
          size_t q = ((size_t)(b * HH + h) * SS + sr) * 64 + d;
          split16(o, Ch[q], Cl[q]);
        } else {  // EPI == 2: QKV dispatch
          int reg = col >> 10;  // uniform per block
          int c = col & 1023;
          if (reg == 2) {
            Cf[(size_t)rowr * 1024 + c] = o;  // V fp32 [2048][1024]
          } else {
            if (reg == 0) o *= scale;  // Q pre-scaled
            int b = rowr >> 9, sr = rowr & 511, h = c >> 6, d = c & 63;
            size_t q = ((size_t)(b * HH + h) * SS + sr) * 64 + d;
            if (reg == 0) split16(o, Ch[q], Cl[q]);
            else split16(o, Ch2[q], Cl2[q]);
          }
        }
      }
    }
  }
}

// ---------------- MFMA flash attention (2-phase pipelined) ---------------
// Q/K planes [bh][S][64]; Vt planes [bh][64][S]; AO planes [B*S][1024].
template <int CAUSAL>
__global__ __launch_bounds__(256) void flash_mfma(
    const _Float16* __restrict__ Qph, const _Float16* __restrict__ Qpl,
    const _Float16* __restrict__ Kph, const _Float16* __restrict__ Kpl,
    const _Float16* __restrict__ Vph, const _Float16* __restrict__ Vpl,
    _Float16* __restrict__ AOh, _Float16* __restrict__ AOl,
    const int* __restrict__ mask, int Sk) {
  __shared__ __align__(16) _Float16 sKh[2][4096], sKl[2][4096];
  __shared__ __align__(16) _Float16 sVh[2][4096], sVl[2][4096];
  __shared__ __align__(16) _Float16 sPh[4096], sPl[4096];
  const int tid = threadIdx.x, lane = tid & 63, wid = tid >> 6;
  const int l15 = lane & 15, l4 = lane >> 4;
  const int flat = blockIdx.x;
  const int bh = flat >> 3, b = bh >> 4;
  int qt = flat & 7;
  if (CAUSAL && (flat >> 8)) qt = 7 - qt;  // complement pairing for balance
  const size_t qkb = (size_t)bh * SS * 64;
  const size_t vtb = (size_t)bh * 64 * Sk;

  // per-lane staging geometry (global side per-lane; LDS dest wave-uniform)
  int srow[2], slg[2], sde[2];
#pragma unroll
  for (int c = 0; c < 2; ++c) {
    int u = (c << 8) + tid;
    srow[c] = u >> 3;
    slg[c] = (u & 7) ^ (srow[c] & 7);
    sde[c] = (c << 11) + (wid << 9);
  }

  // Q fragments (registers, from global; L2-resident)
  h8 aqh[2], aql[2];
#pragma unroll
  for (int ks = 0; ks < 2; ++ks) {
    size_t qa = qkb + (size_t)(qt * 64 + wid * 16 + l15) * 64 + ks * 32 + l4 * 8;
    aqh[ks] = *(const h8*)(Qph + qa);
    aql[ks] = *(const h8*)(Qpl + qa);
  }
  f32x4 o_[4];
  float m_[4], l_[4];
#pragma unroll
  for (int i = 0; i < 4; ++i) o_[i] = (f32x4){0.f, 0.f, 0.f, 0.f};
#pragma unroll
  for (int r = 0; r < 4; ++r) { m_[r] = -3.0e38f; l_[r] = 0.f; }

  const int nkt = CAUSAL ? (qt + 1) : (Sk >> 6);
  // prologue: stage tile 0 into buf 0
#pragma unroll
  for (int c = 0; c < 2; ++c) {
    size_t ksrc = qkb + (size_t)(0 * 64 + srow[c]) * 64 + slg[c] * 8;
    size_t vsrc = vtb + (size_t)srow[c] * Sk + 0 * 64 + slg[c] * 8;
    GLD16(Kph + ksrc, &sKh[0][sde[c]]);
    GLD16(Kpl + ksrc, &sKl[0][sde[c]]);
    GLD16(Vph + vsrc, &sVh[0][sde[c]]);
    GLD16(Vpl + vsrc, &sVl[0][sde[c]]);
  }
  __syncthreads();
  int cur = 0;
  for (int kt = 0; kt < nkt; ++kt) {
    if (kt + 1 < nkt) {
#pragma unroll
      for (int c = 0; c < 2; ++c) {
        size_t ksrc = qkb + (size_t)((kt + 1) * 64 + srow[c]) * 64 + slg[c] * 8;
        size_t vsrc = vtb + (size_t)srow[c] * Sk + (kt + 1) * 64 + slg[c] * 8;
        GLD16(Kph + ksrc, &sKh[cur ^ 1][sde[c]]);
        GLD16(Kpl + ksrc, &sKl[cur ^ 1][sde[c]]);
        GLD16(Vph + vsrc, &sVh[cur ^ 1][sde[c]]);
        GLD16(Vpl + vsrc, &sVl[cur ^ 1][sde[c]]);
      }
    }
    // mask values for this tile (per-thread global loads, L2-hot)
    int mv[4];
    if (mask != nullptr) {
#pragma unroll
      for (int fj = 0; fj < 4; ++fj)
        mv[fj] = mask[b * Sk + kt * 64 + fj * 16 + l15];
    }
    const _Float16* pKh = sKh[cur];
    const _Float16* pKl = sKl[cur];
    const _Float16* pVh = sVh[cur];
    const _Float16* pVl = sVl[cur];
    // QK^T (3-product split)
    f32x4 sc[4];
#pragma unroll
    for (int fj = 0; fj < 4; ++fj) {
      sc[fj] = (f32x4){0.f, 0.f, 0.f, 0.f};
#pragma unroll
      for (int ks = 0; ks < 2; ++ks) {
        int off = swzel(fj * 16 + l15, ks * 4 + l4);
        h8 bkh = *(const h8*)&pKh[off];
        h8 bkl = *(const h8*)&pKl[off];
        sc[fj] = __builtin_amdgcn_mfma_f32_16x16x32_f16(aqh[ks], bkh, sc[fj], 0, 0, 0);
        sc[fj] = __builtin_amdgcn_mfma_f32_16x16x32_f16(aql[ks], bkh, sc[fj], 0, 0, 0);
        sc[fj] = __builtin_amdgcn_mfma_f32_16x16x32_f16(aqh[ks], bkl, sc[fj], 0, 0, 0);
      }
    }
    if (CAUSAL && kt == qt) {
#pragma unroll
      for (int fj = 0; fj < 4; ++fj)
#pragma unroll
        for (int r = 0; r < 4; ++r)
          if (fj * 16 + l15 > wid * 16 + l4 * 4 + r) sc[fj][r] = -1e20f;
    }
    if (mask != nullptr) {
#pragma unroll
      for (int fj = 0; fj < 4; ++fj)
        if (mv[fj] == 0) {
#pragma unroll
          for (int r = 0; r < 4; ++r) sc[fj][r] = -1e20f;
        }
    }
    // online softmax rows; write P planes (own rows only -> no barrier)
#pragma unroll
    for (int r = 0; r < 4; ++r) {
      float rm = fmaxf(fmaxf(sc[0][r], sc[1][r]), fmaxf(sc[2][r], sc[3][r]));
#pragma unroll
      for (int mk = 1; mk < 16; mk <<= 1) rm = fmaxf(rm, __shfl_xor(rm, mk));
      float mn = fmaxf(m_[r], rm);
      float f = __expf(m_[r] - mn);
      float rs = 0.f;
      int prow = wid * 16 + l4 * 4 + r;
#pragma unroll
      for (int fj = 0; fj < 4; ++fj) {
        float p = __expf(sc[fj][r] - mn);
        rs += p;
        int col = fj * 16 + l15;
        int el = (prow << 6) + ((((col >> 3) ^ (prow & 7))) << 3) + (col & 7);
        _Float16 ph = (_Float16)p;
        sPh[el] = ph;
        sPl[el] = (_Float16)(p - (float)ph);
      }
#pragma unroll
      for (int mk = 1; mk < 16; mk <<= 1) rs += __shfl_xor(rs, mk);
      l_[r] = l_[r] * f + rs;
      m_[r] = mn;
#pragma unroll
      for (int df = 0; df < 4; ++df) o_[df][r] *= f;
    }
    // PV (3-product split)
#pragma unroll
    for (int ks = 0; ks < 2; ++ks) {
      int poff = swzel(wid * 16 + l15, ks * 4 + l4);
      h8 aph = *(const h8*)&sPh[poff];
      h8 apl = *(const h8*)&sPl[poff];
#pragma unroll
      for (int df = 0; df < 4; ++df) {
        int voff = swzel(df * 16 + l15, ks * 4 + l4);
        h8 bvh = *(const h8*)&pVh[voff];
        h8 bvl = *(const h8*)&pVl[voff];
        o_[df] = __builtin_amdgcn_mfma_f32_16x16x32_f16(aph, bvh, o_[df], 0, 0, 0);
        o_[df] = __builtin_amdgcn_mfma_f32_16x16x32_f16(apl, bvh, o_[df], 0, 0, 0);
        o_[df] = __builtin_amdgcn_mfma_f32_16x16x32_f16(aph, bvl, o_[df], 0, 0, 0);
      }
    }
    __syncthreads();  // drains prefetch; guards K/V buffer reuse
    cur ^= 1;
  }
  // epilogue -> AO planes [B*S][1024]
#pragma unroll
  for (int r = 0; r < 4; ++r) {
    float inv = 1.0f / l_[r];
    int row = qt * 64 + wid * 16 + l4 * 4 + r;
    size_t ob = ((size_t)b * SS + row) * DD + (bh & 15) * 64;
#pragma unroll
    for (int df = 0; df < 4; ++df) {
      float o = o_[df][r] * inv;
      split16(o, AOh[ob + df * 16 + l15], AOl[ob + df * 16 + l15]);
    }
  }
}

// --------------------------------------------------------------------------
extern "C" void kernel_launch(void* const* d_in, const int* in_sizes, int n_in,
                              void* d_out, int out_size, void* d_ws,
                              size_t ws_size, hipStream_t stream) {
  const int* tokens = (const int*)d_in[0];
  const float* enc = (const float*)d_in[1];
  const int* encmask = (const int*)d_in[2];
  const float* emb = (const float*)d_in[3];
  const float* sa_qw = (const float*)d_in[4];
  const float* sa_qb = (const float*)d_in[5];
  const float* sa_kw = (const float*)d_in[6];
  const float* sa_kb = (const float*)d_in[7];
  const float* sa_vw = (const float*)d_in[8];
  const float* sa_vb = (const float*)d_in[9];
  const float* sa_ow = (const float*)d_in[10];
  const float* sa_ob = (const float*)d_in[11];
  const float* ca_qw = (const float*)d_in[12];
  const float* ca_qb = (const float*)d_in[13];
  const float* ca_kw = (const float*)d_in[14];
  const float* ca_kb = (const float*)d_in[15];
  const float* ca_vw = (const float*)d_in[16];
  const float* ca_vb = (const float*)d_in[17];
  const float* ca_ow = (const float*)d_in[18];
  const float* ca_ob = (const float*)d_in[19];
  const float* ln1_g = (const float*)d_in[20];
  const float* ln1_b = (const float*)d_in[21];
  const float* ln2_g = (const float*)d_in[22];
  const float* ln2_b = (const float*)d_in[23];
  const float* ln3_g = (const float*)d_in[24];
  const float* ln3_b = (const float*)d_in[25];
  const float* ff_w1 = (const float*)d_in[26];
  const float* ff_b1 = (const float*)d_in[27];
  const float* ff_w2 = (const float*)d_in[28];
  const float* ff_b2 = (const float*)d_in[29];
  const float* act_w = (const float*)d_in[30];
  const float* act_b = (const float*)d_in[31];
  float* out = (float*)d_out;

  const size_t nbsd = (size_t)BB * SS * DD;  // 2097152
  const size_t nff = (size_t)BB * SS * FFD;  // 8388608
  const size_t nbs = (size_t)BB * SS;        // 2048
  const size_t wsm = (size_t)DD * DD;
  const size_t wff = (size_t)DD * FFD;

  // ---- fp32 region ----
  float* w = (float*)d_ws;
  float* POS = w;  w += (size_t)SS * DD;
  float* TIM = w;  w += (size_t)NHOP * DD;
  float* TEN = w;  w += nbsd;
  float* PR = w;   w += nbsd;
  float* QKV = w;  w += (size_t)2048 * 3072;  // VF32 in [0,nbsd); T2 planes above
  float* QKVB = w; w += 3072;
  float* HPp = w;  w += nbs;
  float* REMp = w; w += nbs;
  float* UWp = w;  w += nbs;
  // ---- fp16 region ----
  _Float16* hp16 = (_Float16*)w;
  auto halloc = [&](size_t n) { _Float16* r = hp16; hp16 += n; return r; };
  _Float16* TINh = halloc(nbsd); _Float16* TINl = halloc(nbsd);
  _Float16* AOh = halloc(nbsd);  _Float16* AOl = halloc(nbsd);
  _Float16* FFHh = halloc(nff);  _Float16* FFHl = halloc(nff);
  _Float16* qkvWh = halloc(3 * wsm); _Float16* qkvWl = halloc(3 * wsm);
  _Float16* saoWh = halloc(wsm); _Float16* saoWl = halloc(wsm);
  _Float16* caqWh = halloc(wsm); _Float16* caqWl = halloc(wsm);
  _Float16* caoWh = halloc(wsm); _Float16* caoWl = halloc(wsm);
  _Float16* ff1Wh = halloc(wff); _Float16* ff1Wl = halloc(wff);
  _Float16* ff2Wh = halloc(wff); _Float16* ff2Wl = halloc(wff);
  _Float16* EKh = halloc(nbsd); _Float16* EKl = halloc(nbsd);
  _Float16* EVh = halloc(nbsd); _Float16* EVl = halloc(nbsd);
  size_t need = (size_t)((char*)hp16 - (char*)d_ws);
  if (ws_size < need) return;

  // lifetime-disjoint aliases:
  float* VF32 = QKV;                                   // [2048][1024] fp32
  _Float16* T3h = TINh; _Float16* T3l = TINl;          // after ln2
  _Float16* T2h = (_Float16*)(QKV + nbsd);             // above VF32
  _Float16* T2l = (_Float16*)(QKV + nbsd + nbsd / 2);
  // attention planes alias FFH (dead during attention phase)
  _Float16* Qph = FFHh;             _Float16* Qpl = FFHh + nbsd;
  _Float16* Kph = FFHh + 2 * nbsd;  _Float16* Kpl = FFHh + 3 * nbsd;
  _Float16* Vph = FFHl;             _Float16* Vpl = FFHl + nbsd;
  _Float16* CQh = FFHl + 2 * nbsd;  _Float16* CQl = FFHl + 3 * nbsd;

  hipMemsetAsync(d_out, 0, nbsd * sizeof(float), stream);
  hipMemsetAsync(HPp, 0, 2 * nbs * sizeof(float), stream);
  sincos_kernel<<<dim3(512), dim3(256), 0, stream>>>(POS, SS * DD);
  sincos_kernel<<<dim3(24), dim3(256), 0, stream>>>(TIM, NHOP * DD);
  embed_kernel<<<dim3(2048), dim3(256), 0, stream>>>(tokens, emb, TEN, (int)nbsd);
  asplit_kernel<<<dim3(2048), dim3(256), 0, stream>>>(enc, TINh, TINl, (int)nbsd);

  auto wsplit = [&](const float* W, _Float16* h, _Float16* l, int K, int N) {
    wsplit_kernel<<<dim3(N >> 5, K >> 5), dim3(256), 0, stream>>>(W, h, l, K, N);
  };
  wsplit(sa_qw, qkvWh, qkvWl, DD, DD);
  wsplit(sa_kw, qkvWh + wsm, qkvWl + wsm, DD, DD);
  wsplit(sa_vw, qkvWh + 2 * wsm, qkvWl + 2 * wsm, DD, DD);
  wsplit(sa_ow, saoWh, saoWl, DD, DD);
  wsplit(ca_qw, caqWh, caqWl, DD, DD);
  wsplit(ca_kw, FFHh, FFHh + wsm, DD, DD);              // temp in FFH
  wsplit(ca_vw, FFHh + 2 * wsm, FFHh + 3 * wsm, DD, DD);
  wsplit(ca_ow, caoWh, caoWl, DD, DD);
  wsplit(ff_w1, ff1Wh, ff1Wl, DD, FFD);
  wsplit(ff_w2, ff2Wh, ff2Wl, FFD, DD);
  concat3_kernel<<<dim3(12), dim3(256), 0, stream>>>(sa_qb, sa_kb, sa_vb, QKVB);

  auto gemmF = [&](const _Float16* ah, const _Float16* al, const _Float16* bh,
                   const _Float16* bl, const float* bi, float* cf, int M, int N,
                   int K) {
    gemm_pl<0><<<dim3(N >> 6, M >> 6), dim3(256), 0, stream>>>(
        ah, al, bh, bl, bi, cf, nullptr, nullptr, nullptr, nullptr, M, N, K,
        1.f);
  };

  // hoisted: encoder K -> EK planes directly; V -> fp32 then transpose
  gemm_pl<3><<<dim3(16, 32), dim3(256), 0, stream>>>(
      TINh, TINl, FFHh, FFHh + wsm, ca_kb, nullptr, EKh, EKl, nullptr, nullptr,
      2048, DD, DD, 1.f);
  gemmF(TINh, TINl, FFHh + 2 * wsm, FFHh + 3 * wsm, ca_vb, VF32, 2048, DD, DD);
  prep_vt_kernel<<<dim3(8, 64), dim3(256), 0, stream>>>(VF32, DD, 0, EVh, EVl);

  for (int t = 0; t < NHOP; ++t) {
    addcodes_kernel<<<dim3(2048), dim3(256), 0, stream>>>(TINh, TINl, TEN, POS,
                                                          TIM, t, (int)nbsd);
    act_kernel<<<dim3(2048), dim3(256), 0, stream>>>(TINh, TINl, act_w, act_b,
                                                     HPp, REMp, UWp);
    // fused QKV projection -> Q/K planes + V fp32
    gemm_pl<2><<<dim3(48, 32), dim3(256), 0, stream>>>(
        TINh, TINl, qkvWh, qkvWl, QKVB, VF32, Qph, Qpl, Kph, Kpl, 2048, 3072,
        DD, 0.125f);
    prep_vt_kernel<<<dim3(8, 64), dim3(256), 0, stream>>>(VF32, DD, 0, Vph, Vpl);
    flash_mfma<1><<<dim3(512), dim3(256), 0, stream>>>(
        Qph, Qpl, Kph, Kpl, Vph, Vpl, AOh, AOl, nullptr, SS);
    gemmF(AOh, AOl, saoWh, saoWl, sa_ob, PR, 2048, DD, DD);
    lnres_kernel<<<dim3(2048), dim3(256), 0, stream>>>(
        PR, TINh, TINl, ln1_g, ln1_b, nullptr, T2h, T2l, nullptr, nullptr, 1);
    // cross-attention: caq -> CQ planes directly
    gemm_pl<3><<<dim3(16, 32), dim3(256), 0, stream>>>(
        T2h, T2l, caqWh, caqWl, ca_qb, nullptr, CQh, CQl, nullptr, nullptr,
        2048, DD, DD, 0.125f);
    flash_mfma<0><<<dim3(512), dim3(256), 0, stream>>>(
        CQh, CQl, EKh, EKl, EVh, EVl, AOh, AOl, encmask, SE);
    gemmF(AOh, AOl, caoWh, caoWl, ca_ob, PR, 2048, DD, DD);
    lnres_kernel<<<dim3(2048), dim3(256), 0, stream>>>(
        PR, T2h, T2l, ln2_g, ln2_b, nullptr, T3h, T3l, nullptr, nullptr, 1);
    // FFN
    gemm_pl<1><<<dim3(64, 32), dim3(256), 0, stream>>>(
        T3h, T3l, ff1Wh, ff1Wl, ff_b1, nullptr, FFHh, FFHl, nullptr, nullptr,
        2048, FFD, DD, 1.f);
    gemmF(FFHh, FFHl, ff2Wh, ff2Wl, ff_b2, PR, 2048, DD, FFD);
    // ln3 + fused prev update
    lnres_kernel<<<dim3(2048), dim3(256), 0, stream>>>(
        PR, T3h, T3l, ln3_g, ln3_b, TEN, nullptr, nullptr, UWp, out, 0);
  }
}